// Round 1
// baseline (759.711 us; speedup 1.0000x reference)
//
#include <hip/hip_runtime.h>

// ---------------------------------------------------------------------------
// FPSAttn: the reference's LSH/permutation machinery is a mathematical no-op
// (attention is over the whole permuted 64-token patch, then inverse-permuted;
// both rounds are identical and probs==0.5). So we compute:
//   spa  = patchwise 4-head softmax attention (64 tok, d=48) + Wo projection
//   freq = FMAM global-context module
//   out  = spa*dw[:,0] + freq*dw[:,1]
// All fp32 (CDNA4 has no fp32 MFMA; vector ALU).
// ---------------------------------------------------------------------------

// ======================= Patch attention kernel ============================
// One block (256 thr) per patch. LDS strides chosen for <=2-way bank aliasing:
//   xpT [64][64]  (c-major)        q/k/v [64][52]   p [64][65] / o [64][53]
__global__ __launch_bounds__(256) void attn_kernel(
    const float* __restrict__ x, const float* __restrict__ Wq,
    const float* __restrict__ Wk, const float* __restrict__ Wv,
    const float* __restrict__ Wo, float* __restrict__ spa)
{
  extern __shared__ float sm[];
  float* xpT   = sm;                    // [64][64]  xpT[c*64+t]
  float* q_lds = sm + 64 * 64;          // [64][52]
  float* k_lds = q_lds + 64 * 52;
  float* v_lds = k_lds + 64 * 52;
  float* p_lds = v_lds + 64 * 52;       // [64][65]; reused as o at stride 53

  const int tid  = threadIdx.x;
  const int pid  = blockIdx.x;
  const int b    = pid >> 10;           // 1024 patches per batch
  const int prem = pid & 1023;
  const int y0   = (prem >> 5) << 3;
  const int x0   = (prem & 31) << 3;
  const float* xb = x + ((size_t)b << 22);   // b*64*65536

  // load patch, transposed to xpT[c][t]  (t = py*8+px)
#pragma unroll
  for (int k = 0; k < 16; ++k) {
    int idx = tid + (k << 8);
    int c = idx >> 6, t = idx & 63;
    xpT[idx] = xb[((size_t)c << 16) + (size_t)((y0 + (t >> 3)) * 256 + x0 + (t & 7))];
  }

  const int tg15 = tid & 15;   // t-group for qkv/PV/out stages
  const int g4   = tid >> 4;   // 0..15

  float outacc[4][4];
#pragma unroll
  for (int a = 0; a < 4; ++a)
#pragma unroll
    for (int c = 0; c < 4; ++c) outacc[a][c] = 0.f;

  for (int h = 0; h < 4; ++h) {
    __syncthreads();
    // ---------------- QKV: thread tile 4 tokens x 3 cols ----------------
    {
      const int t0  = tg15 << 2;
      const int j0  = g4 * 3;
      const int col = h * 48 + j0;
      float qa[4][3], ka[4][3], va[4][3];
#pragma unroll
      for (int tt = 0; tt < 4; ++tt)
#pragma unroll
        for (int jj = 0; jj < 3; ++jj) { qa[tt][jj] = 0.f; ka[tt][jj] = 0.f; va[tt][jj] = 0.f; }
      for (int c = 0; c < 64; ++c) {
        const float4 xv = *(const float4*)&xpT[(c << 6) + t0];
        const float* wq = Wq + c * 192 + col;
        const float* wk = Wk + c * 192 + col;
        const float* wv = Wv + c * 192 + col;
#pragma unroll
        for (int jj = 0; jj < 3; ++jj) {
          const float a0 = wq[jj], a1 = wk[jj], a2 = wv[jj];
          qa[0][jj] += xv.x * a0; qa[1][jj] += xv.y * a0; qa[2][jj] += xv.z * a0; qa[3][jj] += xv.w * a0;
          ka[0][jj] += xv.x * a1; ka[1][jj] += xv.y * a1; ka[2][jj] += xv.z * a1; ka[3][jj] += xv.w * a1;
          va[0][jj] += xv.x * a2; va[1][jj] += xv.y * a2; va[2][jj] += xv.z * a2; va[3][jj] += xv.w * a2;
        }
      }
#pragma unroll
      for (int tt = 0; tt < 4; ++tt)
#pragma unroll
        for (int jj = 0; jj < 3; ++jj) {
          q_lds[(t0 + tt) * 52 + j0 + jj] = qa[tt][jj];
          k_lds[(t0 + tt) * 52 + j0 + jj] = ka[tt][jj];
          v_lds[(t0 + tt) * 52 + j0 + jj] = va[tt][jj];
        }
    }
    __syncthreads();
    // -------- S = q k^T (4t x 4u tile), softmax over u, write P ---------
    {
      const int t0 = g4 << 2;      // rows
      const int m  = tg15;         // u = 16*uu + m
      float s[4][4];
#pragma unroll
      for (int tt = 0; tt < 4; ++tt)
#pragma unroll
        for (int uu = 0; uu < 4; ++uu) s[tt][uu] = 0.f;
      for (int j4 = 0; j4 < 48; j4 += 4) {
        float4 q4[4], k4[4];
#pragma unroll
        for (int tt = 0; tt < 4; ++tt) q4[tt] = *(const float4*)&q_lds[(t0 + tt) * 52 + j4];
#pragma unroll
        for (int uu = 0; uu < 4; ++uu) k4[uu] = *(const float4*)&k_lds[((uu << 4) + m) * 52 + j4];
#pragma unroll
        for (int tt = 0; tt < 4; ++tt)
#pragma unroll
          for (int uu = 0; uu < 4; ++uu)
            s[tt][uu] += q4[tt].x * k4[uu].x + q4[tt].y * k4[uu].y +
                         q4[tt].z * k4[uu].z + q4[tt].w * k4[uu].w;
      }
      float lm[4], ls[4];
#pragma unroll
      for (int tt = 0; tt < 4; ++tt)
        lm[tt] = fmaxf(fmaxf(s[tt][0], s[tt][1]), fmaxf(s[tt][2], s[tt][3]));
      for (int msk = 1; msk <= 8; msk <<= 1) {
#pragma unroll
        for (int tt = 0; tt < 4; ++tt) lm[tt] = fmaxf(lm[tt], __shfl_xor(lm[tt], msk, 64));
      }
      float e[4][4];
#pragma unroll
      for (int tt = 0; tt < 4; ++tt) {
        ls[tt] = 0.f;
#pragma unroll
        for (int uu = 0; uu < 4; ++uu) { e[tt][uu] = __expf(s[tt][uu] - lm[tt]); ls[tt] += e[tt][uu]; }
      }
      for (int msk = 1; msk <= 8; msk <<= 1) {
#pragma unroll
        for (int tt = 0; tt < 4; ++tt) ls[tt] += __shfl_xor(ls[tt], msk, 64);
      }
#pragma unroll
      for (int tt = 0; tt < 4; ++tt) {
        const float ri = 1.f / ls[tt];
#pragma unroll
        for (int uu = 0; uu < 4; ++uu)
          p_lds[(t0 + tt) * 65 + (uu << 4) + m] = e[tt][uu] * ri;
      }
    }
    __syncthreads();
    // ---------------- O = P V (4t x 3j tile) ----------------
    {
      const int t0 = tg15 << 2;
      const int j0 = g4 * 3;
      float oa[4][3];
#pragma unroll
      for (int tt = 0; tt < 4; ++tt)
#pragma unroll
        for (int jj = 0; jj < 3; ++jj) oa[tt][jj] = 0.f;
      for (int u = 0; u < 64; ++u) {
        float pv[4];
#pragma unroll
        for (int tt = 0; tt < 4; ++tt) pv[tt] = p_lds[(t0 + tt) * 65 + u];
        const float v0 = v_lds[u * 52 + j0], v1 = v_lds[u * 52 + j0 + 1], v2 = v_lds[u * 52 + j0 + 2];
#pragma unroll
        for (int tt = 0; tt < 4; ++tt) {
          oa[tt][0] += pv[tt] * v0; oa[tt][1] += pv[tt] * v1; oa[tt][2] += pv[tt] * v2;
        }
      }
      __syncthreads();   // all P reads done; reuse p region for O (stride 53)
#pragma unroll
      for (int tt = 0; tt < 4; ++tt)
#pragma unroll
        for (int jj = 0; jj < 3; ++jj)
          p_lds[(t0 + tt) * 53 + j0 + jj] = oa[tt][jj];
    }
    __syncthreads();
    // -------- out += O @ Wo[h-slice]  (4t x 4co tile, Wo from L2) --------
    {
      const int t0  = tg15 << 2;
      const int co0 = g4 << 2;
      for (int j = 0; j < 48; ++j) {
        float ov[4];
#pragma unroll
        for (int tt = 0; tt < 4; ++tt) ov[tt] = p_lds[(t0 + tt) * 53 + j];
        const float4 w4 = *(const float4*)&Wo[((h * 48 + j) << 6) + co0];
#pragma unroll
        for (int tt = 0; tt < 4; ++tt) {
          outacc[tt][0] += ov[tt] * w4.x; outacc[tt][1] += ov[tt] * w4.y;
          outacc[tt][2] += ov[tt] * w4.z; outacc[tt][3] += ov[tt] * w4.w;
        }
      }
    }
  }
  // ---------------- write spa (float4 along x) ----------------
  {
    const int t0 = tg15 << 2;                 // same py, px0..px0+3
    const int py = t0 >> 3, px0 = t0 & 7;
    float* sb = spa + ((size_t)b << 22) + (size_t)((y0 + py) * 256 + x0 + px0);
#pragma unroll
    for (int cc = 0; cc < 4; ++cc) {
      float4 vv = make_float4(outacc[0][cc], outacc[1][cc], outacc[2][cc], outacc[3][cc]);
      *(float4*)(sb + ((size_t)((g4 << 2) + cc) << 16)) = vv;
    }
  }
}

// ======================= FMAM: key-softmax stats ===========================
// Y[o,n] = fmam_w[o,:].x[:,n] + fb[o]; per (b,o): running max & sum(exp).
// Grid (256 chunks, 2 b); chunk = 256 positions, 2 subtiles of 128.
__global__ __launch_bounds__(256) void fmam_kstats(
    const float* __restrict__ x, const float* __restrict__ fw,
    const float* __restrict__ fb, float* __restrict__ kpart)
{
  __shared__ float xt[64 * 128];
  __shared__ float wl[64 * 65];
  __shared__ float red[4 * 64 * 2];
  const int tid = threadIdx.x;
  const int chunk = blockIdx.x, b = blockIdx.y;
  const float* xb = x + ((size_t)b << 22);
#pragma unroll
  for (int k = 0; k < 16; ++k) {
    int idx = tid + (k << 8); int o = idx >> 6, c = idx & 63;
    wl[o * 65 + c] = fw[idx];
  }
  const int o = tid & 63, ng = tid >> 6;
  const float bias = fb[o];
  float m = -1e30f, s = 0.f;
  for (int st = 0; st < 2; ++st) {
    __syncthreads();
    const int n0 = (chunk << 8) + (st << 7);
#pragma unroll
    for (int k = 0; k < 32; ++k) {
      int idx = tid + (k << 8); int c = idx >> 7, nn = idx & 127;
      xt[idx] = xb[((size_t)c << 16) + (size_t)(n0 + nn)];
    }
    __syncthreads();
    float acc[32];
#pragma unroll
    for (int i = 0; i < 32; ++i) acc[i] = bias;
    const float* wrow = &wl[o * 65];
    for (int c = 0; c < 64; ++c) {
      const float wv = wrow[c];
      const float4* xr = (const float4*)&xt[(c << 7) + (ng << 5)];
#pragma unroll
      for (int q = 0; q < 8; ++q) {
        const float4 xv = xr[q];
        acc[q * 4 + 0] += wv * xv.x; acc[q * 4 + 1] += wv * xv.y;
        acc[q * 4 + 2] += wv * xv.z; acc[q * 4 + 3] += wv * xv.w;
      }
    }
    float lm = acc[0];
#pragma unroll
    for (int i = 1; i < 32; ++i) lm = fmaxf(lm, acc[i]);
    const float nm = fmaxf(m, lm);
    float ls = 0.f;
#pragma unroll
    for (int i = 0; i < 32; ++i) ls += __expf(acc[i] - nm);
    s = s * __expf(m - nm) + ls;
    m = nm;
  }
  __syncthreads();
  red[((ng << 6) + o) * 2] = m; red[((ng << 6) + o) * 2 + 1] = s;
  __syncthreads();
  if (tid < 64) {
    float M = red[tid * 2], S = red[tid * 2 + 1];
#pragma unroll
    for (int g = 1; g < 4; ++g) {
      const float m2 = red[((g << 6) + tid) * 2], s2 = red[((g << 6) + tid) * 2 + 1];
      const float nm = fmaxf(M, m2);
      S = S * __expf(M - nm) + s2 * __expf(m2 - nm);
      M = nm;
    }
    kpart[(((b << 8) + chunk) * 64 + tid) * 2]     = M;
    kpart[(((b << 8) + chunk) * 64 + tid) * 2 + 1] = S;
  }
}

// =================== FMAM: combine per-chunk stats =========================
__global__ void fmam_kreduce(const float* __restrict__ kpart, float* __restrict__ kstats)
{
  const int bo = blockIdx.x;       // b*64+o (128 blocks)
  const int b = bo >> 6, o = bo & 63;
  const int lane = threadIdx.x;    // 64
  float M = -1e30f, S = 0.f;
  for (int ch = lane; ch < 256; ch += 64) {
    const float* pp = kpart + ((size_t)(((b << 8) + ch) * 64 + o)) * 2;
    const float m2 = pp[0], s2 = pp[1];
    const float nm = fmaxf(M, m2);
    S = S * __expf(M - nm) + s2 * __expf(m2 - nm);
    M = nm;
  }
  for (int msk = 1; msk < 64; msk <<= 1) {
    const float m2 = __shfl_xor(M, msk, 64);
    const float s2 = __shfl_xor(S, msk, 64);
    const float nm = fmaxf(M, m2);
    S = S * __expf(M - nm) + s2 * __expf(m2 - nm);
    M = nm;
  }
  if (lane == 0) { kstats[bo * 2] = M; kstats[bo * 2 + 1] = 1.f / S; }
}

// =================== FMAM: ctx partials ====================================
// ctx[b,c,o] = sum_n x[c,n] * exp(Y[o,n]-M)/S ; per-chunk partials.
__global__ __launch_bounds__(256) void fmam_ctx(
    const float* __restrict__ x, const float* __restrict__ fw,
    const float* __restrict__ fb, const float* __restrict__ kstats,
    float* __restrict__ ctxpart)
{
  __shared__ float xt[64 * 128];
  __shared__ float wl[64 * 65];
  const int tid = threadIdx.x;
  const int chunk = blockIdx.x, b = blockIdx.y;
  const float* xb = x + ((size_t)b << 22);
#pragma unroll
  for (int k = 0; k < 16; ++k) {
    int idx = tid + (k << 8); int o = idx >> 6, c = idx & 63;
    wl[o * 65 + c] = fw[idx];
  }
  const int o = tid & 63, ng = tid >> 6;
  const float bias = fb[o];
  const float M  = kstats[((b << 6) + o) * 2];
  const float IS = kstats[((b << 6) + o) * 2 + 1];
  float cacc[64];
#pragma unroll
  for (int i = 0; i < 64; ++i) cacc[i] = 0.f;
  for (int st = 0; st < 2; ++st) {
    __syncthreads();
    const int n0 = (chunk << 8) + (st << 7);
#pragma unroll
    for (int k = 0; k < 32; ++k) {
      int idx = tid + (k << 8); int c = idx >> 7, nn = idx & 127;
      xt[idx] = xb[((size_t)c << 16) + (size_t)(n0 + nn)];
    }
    __syncthreads();
    float acc[32];
#pragma unroll
    for (int i = 0; i < 32; ++i) acc[i] = bias;
    const float* wrow = &wl[o * 65];
    for (int c = 0; c < 64; ++c) {
      const float wv = wrow[c];
      const float4* xr = (const float4*)&xt[(c << 7) + (ng << 5)];
#pragma unroll
      for (int q = 0; q < 8; ++q) {
        const float4 xv = xr[q];
        acc[q * 4 + 0] += wv * xv.x; acc[q * 4 + 1] += wv * xv.y;
        acc[q * 4 + 2] += wv * xv.z; acc[q * 4 + 3] += wv * xv.w;
      }
    }
#pragma unroll
    for (int i = 0; i < 32; ++i) acc[i] = __expf(acc[i] - M) * IS;   // p values
#pragma unroll
    for (int c = 0; c < 64; ++c) {
      const float4* xr = (const float4*)&xt[(c << 7) + (ng << 5)];
      float s0 = 0.f, s1 = 0.f, s2 = 0.f, s3 = 0.f;
#pragma unroll
      for (int q = 0; q < 8; ++q) {
        const float4 xv = xr[q];
        s0 += xv.x * acc[q * 4 + 0]; s1 += xv.y * acc[q * 4 + 1];
        s2 += xv.z * acc[q * 4 + 2]; s3 += xv.w * acc[q * 4 + 3];
      }
      cacc[c] += (s0 + s1) + (s2 + s3);
    }
  }
  // reduce over ng (4) in 4 c-slices using xt as scratch: red[ng][o][16]
  float* red = xt;
#pragma unroll
  for (int cs = 0; cs < 4; ++cs) {
    __syncthreads();
#pragma unroll
    for (int i = 0; i < 16; ++i) red[((ng << 6) + o) * 16 + i] = cacc[(cs << 4) + i];
    __syncthreads();
#pragma unroll
    for (int t = 0; t < 4; ++t) {
      const int v = tid * 4 + t;            // 0..1023 over [o2][i2]
      const int o2 = v >> 4, i2 = v & 15;
      const float sum = red[((0 << 6) + o2) * 16 + i2] + red[((1 << 6) + o2) * 16 + i2] +
                        red[((2 << 6) + o2) * 16 + i2] + red[((3 << 6) + o2) * 16 + i2];
      ctxpart[((((size_t)b << 8) + chunk) << 12) + (o2 << 6) + (cs << 4) + i2] = sum;
    }
  }
}

// =================== FMAM: reduce ctx partials =============================
__global__ __launch_bounds__(256) void fmam_ctxreduce(
    const float* __restrict__ ctxpart, float* __restrict__ ctx)
{
  __shared__ float red[256];
  const int bo = blockIdx.x;           // b*64+o (128 blocks)
  const int b = bo >> 6, o = bo & 63;
  const int tid = threadIdx.x;
  const int c = tid & 63, cg = tid >> 6;
  const float* p = ctxpart + ((size_t)b << 20) + (o << 6) + c;
  float s = 0.f;
  for (int ch = cg * 64; ch < cg * 64 + 64; ++ch) s += p[(size_t)ch << 12];
  red[tid] = s;
  __syncthreads();
  if (tid < 64) {
    const float v = red[tid] + red[tid + 64] + red[tid + 128] + red[tid + 192];
    ctx[((size_t)bo << 6) + tid] = v;    // ctx[b][o][c]
  }
}

// ============ FMAM: queries softmax + freq + final combine =================
// thread <- one position n; z[o] = q_w@x + qb; softmax over o; freq = ctx^T q;
// out = spa*dw0 + freq*dw1.
__global__ __launch_bounds__(256) void fmam_freq_combine(
    const float* __restrict__ x, const float* __restrict__ qw,
    const float* __restrict__ qb, const float* __restrict__ ctx,
    const float* __restrict__ spa, const float* __restrict__ dw,
    float* __restrict__ out)
{
  extern __shared__ float sm[];
  float* xl   = sm;                 // [64][256] ; later reused for queries
  float* qwT  = sm + 64 * 256;      // [c][68]
  float* ctxl = qwT + 64 * 68;      // [c][68]  ctxl[c][k] = ctx[b][k][c]
  const int tid = threadIdx.x;
  const int chunk = blockIdx.x, b = blockIdx.y;
  const int n0 = chunk << 8;
  const float* xb = x + ((size_t)b << 22);
#pragma unroll
  for (int k = 0; k < 64; ++k) {
    int idx = tid + (k << 8); int c = idx >> 8, nn = idx & 255;
    xl[idx] = xb[((size_t)c << 16) + (size_t)(n0 + nn)];
  }
#pragma unroll
  for (int k = 0; k < 16; ++k) {
    int idx = tid + (k << 8); int o = idx >> 6, c = idx & 63;
    qwT[c * 68 + o]  = qw[idx];
    ctxl[c * 68 + o] = ctx[(((size_t)b << 6) + o) * 64 + c];
  }
  __syncthreads();

  float4 z4[16];
#pragma unroll
  for (int i = 0; i < 16; ++i) {
    z4[i].x = qb[4 * i]; z4[i].y = qb[4 * i + 1]; z4[i].z = qb[4 * i + 2]; z4[i].w = qb[4 * i + 3];
  }
  for (int c = 0; c < 64; ++c) {
    const float xv = xl[(c << 8) + tid];
    const float4* wr = (const float4*)&qwT[c * 68];
#pragma unroll
    for (int i = 0; i < 16; ++i) {
      const float4 w4 = wr[i];
      z4[i].x += w4.x * xv; z4[i].y += w4.y * xv; z4[i].z += w4.z * xv; z4[i].w += w4.w * xv;
    }
  }
  // softmax over the 64 channel logits (all in registers)
  float zm = z4[0].x;
#pragma unroll
  for (int i = 0; i < 16; ++i)
    zm = fmaxf(zm, fmaxf(fmaxf(z4[i].x, z4[i].y), fmaxf(z4[i].z, z4[i].w)));
  float zs = 0.f;
#pragma unroll
  for (int i = 0; i < 16; ++i) {
    z4[i].x = __expf(z4[i].x - zm); z4[i].y = __expf(z4[i].y - zm);
    z4[i].z = __expf(z4[i].z - zm); z4[i].w = __expf(z4[i].w - zm);
    zs += (z4[i].x + z4[i].y) + (z4[i].z + z4[i].w);
  }
  const float ri = 1.f / zs;
  // write queries to own column of xl (column-private; no barrier needed)
#pragma unroll
  for (int i = 0; i < 16; ++i) {
    xl[((4 * i + 0) << 8) + tid] = z4[i].x * ri;
    xl[((4 * i + 1) << 8) + tid] = z4[i].y * ri;
    xl[((4 * i + 2) << 8) + tid] = z4[i].z * ri;
    xl[((4 * i + 3) << 8) + tid] = z4[i].w * ri;
  }
  float4 f4[16];
#pragma unroll
  for (int i = 0; i < 16; ++i) { f4[i].x = 0.f; f4[i].y = 0.f; f4[i].z = 0.f; f4[i].w = 0.f; }
  for (int c = 0; c < 64; ++c) {
    const float qv = xl[(c << 8) + tid];
    const float4* cr = (const float4*)&ctxl[c * 68];
#pragma unroll
    for (int k = 0; k < 16; ++k) {
      const float4 c4 = cr[k];
      f4[k].x += c4.x * qv; f4[k].y += c4.y * qv; f4[k].z += c4.z * qv; f4[k].w += c4.w * qv;
    }
  }
  // combine with spa and write output
  const size_t base = ((size_t)b << 22) + (size_t)(n0 + tid);
#pragma unroll
  for (int i = 0; i < 16; ++i) {
#pragma unroll
    for (int j = 0; j < 4; ++j) {
      const int k = 4 * i + j;
      const float d0 = dw[k * 2], d1 = dw[k * 2 + 1];
      const float fv = (j == 0) ? f4[i].x : (j == 1) ? f4[i].y : (j == 2) ? f4[i].z : f4[i].w;
      const size_t a = base + ((size_t)k << 16);
      out[a] = spa[a] * d0 + fv * d1;
    }
  }
}

// ===========================================================================
extern "C" void kernel_launch(void* const* d_in, const int* in_sizes, int n_in,
                              void* d_out, int out_size, void* d_ws, size_t ws_size,
                              hipStream_t stream) {
  const float* x  = (const float*)d_in[0];
  const float* Wq = (const float*)d_in[1];
  const float* Wk = (const float*)d_in[2];
  const float* Wv = (const float*)d_in[3];
  const float* Wo = (const float*)d_in[4];
  // d_in[5]=alpha, d_in[6]=beta: LSH params, provably no effect on output.
  const float* qw = (const float*)d_in[7];
  const float* qb = (const float*)d_in[8];
  const float* fw = (const float*)d_in[9];
  const float* fb = (const float*)d_in[10];
  const float* dw = (const float*)d_in[11];
  float* out = (float*)d_out;

  float* ws = (float*)d_ws;
  float* spa     = ws;                       // 8388608 f
  float* kpart   = spa + 8388608;            // 2*256*64*2 = 65536 f
  float* kstats  = kpart + 65536;            // 256 f
  float* ctxpart = kstats + 256;             // 2*256*4096 = 2097152 f
  float* ctx     = ctxpart + 2097152;        // 8192 f

  const size_t attn_lds = (size_t)(64 * 64 + 3 * 64 * 52 + 64 * 65) * sizeof(float); // 72960 B
  const size_t f5_lds   = (size_t)(64 * 256 + 2 * 64 * 68) * sizeof(float);          // 100352 B
  (void)hipFuncSetAttribute((const void*)attn_kernel,
                            hipFuncAttributeMaxDynamicSharedMemorySize, (int)attn_lds);
  (void)hipFuncSetAttribute((const void*)fmam_freq_combine,
                            hipFuncAttributeMaxDynamicSharedMemorySize, (int)f5_lds);

  hipLaunchKernelGGL(attn_kernel, dim3(2048), dim3(256), attn_lds, stream,
                     x, Wq, Wk, Wv, Wo, spa);
  hipLaunchKernelGGL(fmam_kstats, dim3(256, 2), dim3(256), 0, stream, x, fw, fb, kpart);
  hipLaunchKernelGGL(fmam_kreduce, dim3(128), dim3(64), 0, stream, kpart, kstats);
  hipLaunchKernelGGL(fmam_ctx, dim3(256, 2), dim3(256), 0, stream, x, fw, fb, kstats, ctxpart);
  hipLaunchKernelGGL(fmam_ctxreduce, dim3(128), dim3(256), 0, stream, ctxpart, ctx);
  hipLaunchKernelGGL(fmam_freq_combine, dim3(256, 2), dim3(256), f5_lds, stream,
                     x, qw, qb, ctx, spa, dw, out);
}

// Round 2
// 367.858 us; speedup vs baseline: 2.0652x; 2.0652x over previous
//
#include <hip/hip_runtime.h>
#include <hip/hip_bf16.h>

// ---------------------------------------------------------------------------
// FPSAttn: LSH/permutation machinery is a mathematical no-op (full attention
// over the permuted 64-token patch, un-permuted after; both rounds identical,
// probs==0.5). Compute:
//   spa  = patchwise 4-head softmax attention (64 tok, d=48) + Wo projection
//          -> bf16 MFMA (error analysis: ~1e-4 max, threshold 7.2e-4)
//   freq = FMAM global-context module (fp32, unchanged this round)
//   out  = spa*dw[:,0] + freq*dw[:,1]
// ---------------------------------------------------------------------------

typedef __attribute__((ext_vector_type(8))) short bf16x8;   // 8 bf16 (4 VGPRs)
typedef __attribute__((ext_vector_type(4))) float f32x4;

static __device__ __forceinline__ short f2bf(float f) {
  __hip_bfloat16 h = __float2bfloat16(f);   // RNE
  return *reinterpret_cast<short*>(&h);
}

// swizzled byte offset into a [rows][64] bf16 LDS tile (128B rows)
#define LSWZ(row, bytecol) (((((row) << 7) + (bytecol))) ^ (((row) & 7) << 4))

// ======================= W prep: transpose + bf16 ==========================
// Wt3[m][dim][c] = W_m[c][dim]  (m: 0=Wq 1=Wk 2=Wv), dim in [0,192), c in [0,64)
// WoTp[h][co][j] = (j<48) ? Wo[h*48+j][co] : 0   (zero-padded K for out-stage)
__global__ __launch_bounds__(256) void prep_w(
    const float* __restrict__ Wq, const float* __restrict__ Wk,
    const float* __restrict__ Wv, const float* __restrict__ Wo,
    short* __restrict__ Wt3, short* __restrict__ WoTp)
{
  int i = blockIdx.x * 256 + threadIdx.x;
  if (i < 36864) {
    int m = i / 12288;
    int r = (i % 12288) >> 6;       // dim 0..191
    int c = i & 63;
    const float* W = (m == 0) ? Wq : (m == 1) ? Wk : Wv;
    Wt3[i] = f2bf(W[c * 192 + r]);
  }
  if (i < 16384) {
    int h = i >> 12, co = (i >> 6) & 63, j = i & 63;
    WoTp[i] = (j < 48) ? f2bf(Wo[(h * 48 + j) * 64 + co]) : (short)0;
  }
}

// ======================= Patch attention (MFMA) ============================
// Block = 1 patch, 4 waves. Heads sequential; wave w owns row/col strip w.
// LDS tiles (all [.][64] bf16, XOR-swizzled rows):
//   xb [64 t][64 c]   qb [64 t][64 d] (cols48-63=0; reused as o[t][j])
//   kb [64 t][64 d] (cols48-63=0)   vb [48 d][64 t]   pb [64 t][64 u]
__global__ __launch_bounds__(256, 4) void attn_mfma(
    const float* __restrict__ x, const short* __restrict__ Wt3,
    const short* __restrict__ WoTp, float* __restrict__ spa)
{
  extern __shared__ char lds[];
  char* xb_ = lds;
  char* qb_ = lds + 8192;
  char* kb_ = lds + 16384;
  char* vb_ = lds + 24576;   // 48 rows
  char* pb_ = lds + 30720;   // total 38912 B

  const int tid  = threadIdx.x;
  const int lane = tid & 63;
  const int w    = tid >> 6;       // wave 0..3
  const int l15  = lane & 15;
  const int l4   = lane >> 4;      // 0..3

  const int pid  = blockIdx.x;
  const int b    = pid >> 10;
  const int prem = pid & 1023;
  const int y0   = (prem >> 5) << 3;
  const int x0   = (prem & 31) << 3;
  const float* xg = x + ((size_t)b << 22);

  // ---- load patch f32 (coalesced 32B runs), convert, store [t][c] ----
#pragma unroll
  for (int k = 0; k < 16; ++k) {
    int idx = tid + (k << 8);
    int c = idx >> 6, t = idx & 63;
    float v = xg[((size_t)c << 16) + (size_t)((y0 + (t >> 3)) * 256 + x0 + (t & 7))];
    *(short*)(xb_ + LSWZ(t, c * 2)) = f2bf(v);
  }
  // zero K-pad cols 48..63 of qb and kb (persist across heads)
#pragma unroll
  for (int i = 0; i < 2; ++i) {
    int idx = tid + (i << 8);             // 0..511
    int row = idx >> 3, dw = idx & 7;
    *(int*)(qb_ + LSWZ(row, 96 + dw * 4)) = 0;
    *(int*)(kb_ + LSWZ(row, 96 + dw * 4)) = 0;
  }
  __syncthreads();

  f32x4 outacc[4];   // out^T tiles: rows co=16w+4*l4+r, cols t=16ct+l15
#pragma unroll
  for (int i = 0; i < 4; ++i) outacc[i] = (f32x4)0.f;

  for (int h = 0; h < 4; ++h) {
    // ================= QKV =================
    {
      bf16x8 xf[2];   // x rows l15+16w: A-frag for q/k tiles, B-frag for vT
#pragma unroll
      for (int ks = 0; ks < 2; ++ks)
        xf[ks] = *(const bf16x8*)(xb_ + LSWZ(l15 + 16 * w, 16 * l4 + 64 * ks));
      // q,k tiles: rt=w, ct=0..2 ; D[t][d] = sum_c x[t][c] * W[c][d]
#pragma unroll
      for (int m = 0; m < 2; ++m) {
        const short* WT = Wt3 + m * 12288;
        char* dst = m ? kb_ : qb_;
#pragma unroll
        for (int ct = 0; ct < 3; ++ct) {
          f32x4 acc = (f32x4)0.f;
          const int dimrow = l15 + 16 * (h * 3 + ct);
#pragma unroll
          for (int ks = 0; ks < 2; ++ks) {
            bf16x8 bf = *(const bf16x8*)(WT + dimrow * 64 + 8 * l4 + 32 * ks);
            acc = __builtin_amdgcn_mfma_f32_16x16x32_bf16(xf[ks], bf, acc, 0, 0, 0);
          }
#pragma unroll
          for (int r = 0; r < 4; ++r)
            *(short*)(dst + LSWZ(16 * w + 4 * l4 + r, (16 * ct + l15) * 2)) = f2bf(acc[r]);
        }
      }
      // vT tiles: ct=w (B=xf), rt=0..2 ; vT[d][t] = sum_c WvT[d][c] x[t][c]
#pragma unroll
      for (int rt = 0; rt < 3; ++rt) {
        f32x4 acc = (f32x4)0.f;
        const int dimrow = l15 + 16 * (h * 3 + rt);
#pragma unroll
        for (int ks = 0; ks < 2; ++ks) {
          bf16x8 af = *(const bf16x8*)(Wt3 + 2 * 12288 + dimrow * 64 + 8 * l4 + 32 * ks);
          acc = __builtin_amdgcn_mfma_f32_16x16x32_bf16(af, xf[ks], acc, 0, 0, 0);
        }
#pragma unroll
        for (int r = 0; r < 4; ++r)
          *(short*)(vb_ + LSWZ(16 * rt + 4 * l4 + r, (16 * w + l15) * 2)) = f2bf(acc[r]);
      }
    }
    __syncthreads();
    // ================= S = q k^T ; softmax -> P =================
    {
      bf16x8 qf[2];
#pragma unroll
      for (int ks = 0; ks < 2; ++ks)
        qf[ks] = *(const bf16x8*)(qb_ + LSWZ(l15 + 16 * w, 16 * l4 + 64 * ks));
      f32x4 s[4];
#pragma unroll
      for (int ct = 0; ct < 4; ++ct) {
        f32x4 acc = (f32x4)0.f;
#pragma unroll
        for (int ks = 0; ks < 2; ++ks) {
          bf16x8 kf = *(const bf16x8*)(kb_ + LSWZ(l15 + 16 * ct, 16 * l4 + 64 * ks));
          acc = __builtin_amdgcn_mfma_f32_16x16x32_bf16(qf[ks], kf, acc, 0, 0, 0);
        }
        s[ct] = acc;
      }
      // rows: 16w + 4*l4 + r over 16 lanes (l15) x 4 ct
#pragma unroll
      for (int r = 0; r < 4; ++r) {
        float m = fmaxf(fmaxf(s[0][r], s[1][r]), fmaxf(s[2][r], s[3][r]));
        for (int msk = 1; msk <= 8; msk <<= 1) m = fmaxf(m, __shfl_xor(m, msk, 64));
        float e0 = __expf(s[0][r] - m), e1 = __expf(s[1][r] - m);
        float e2 = __expf(s[2][r] - m), e3 = __expf(s[3][r] - m);
        float sum = (e0 + e1) + (e2 + e3);
        for (int msk = 1; msk <= 8; msk <<= 1) sum += __shfl_xor(sum, msk, 64);
        const float ri = 1.f / sum;
        const int row = 16 * w + 4 * l4 + r;
        *(short*)(pb_ + LSWZ(row, (l15) * 2))      = f2bf(e0 * ri);
        *(short*)(pb_ + LSWZ(row, (l15 + 16) * 2)) = f2bf(e1 * ri);
        *(short*)(pb_ + LSWZ(row, (l15 + 32) * 2)) = f2bf(e2 * ri);
        *(short*)(pb_ + LSWZ(row, (l15 + 48) * 2)) = f2bf(e3 * ri);
      }
    }
    __syncthreads();
    // ================= oT = vT @ P^T  (write o[t][j] into qb) =============
    {
      bf16x8 pf[2];
#pragma unroll
      for (int ks = 0; ks < 2; ++ks)
        pf[ks] = *(const bf16x8*)(pb_ + LSWZ(l15 + 16 * w, 16 * l4 + 64 * ks));
#pragma unroll
      for (int rt = 0; rt < 3; ++rt) {
        f32x4 acc = (f32x4)0.f;
#pragma unroll
        for (int ks = 0; ks < 2; ++ks) {
          bf16x8 vf = *(const bf16x8*)(vb_ + LSWZ(l15 + 16 * rt, 16 * l4 + 64 * ks));
          acc = __builtin_amdgcn_mfma_f32_16x16x32_bf16(vf, pf[ks], acc, 0, 0, 0);
        }
        // oT[dim=16rt+4*l4+r][t=16w+l15] -> o stored [t][dim]
#pragma unroll
        for (int r = 0; r < 4; ++r)
          *(short*)(qb_ + LSWZ(16 * w + l15, (16 * rt + 4 * l4 + r) * 2)) = f2bf(acc[r]);
      }
    }
    __syncthreads();
    // ================= out^T += WoTp[h] @ o ===============================
    {
#pragma unroll
      for (int ks = 0; ks < 2; ++ks) {
        bf16x8 af = *(const bf16x8*)(WoTp + (h << 12) + (l15 + 16 * w) * 64 + 8 * l4 + 32 * ks);
#pragma unroll
        for (int ct = 0; ct < 4; ++ct) {
          bf16x8 of = *(const bf16x8*)(qb_ + LSWZ(l15 + 16 * ct, 16 * l4 + 64 * ks));
          outacc[ct] = __builtin_amdgcn_mfma_f32_16x16x32_bf16(af, of, outacc[ct], 0, 0, 0);
        }
      }
    }
    __syncthreads();
  }
  // ---- store out^T[co][t] directly into spa[b][co][y][x] ----
  {
    float* sb = spa + ((size_t)b << 22);
#pragma unroll
    for (int ct = 0; ct < 4; ++ct) {
      const int t = 16 * ct + l15;
      const size_t base = (size_t)((y0 + (t >> 3)) * 256 + x0 + (t & 7));
#pragma unroll
      for (int r = 0; r < 4; ++r) {
        const int co = 16 * w + 4 * l4 + r;
        sb[((size_t)co << 16) + base] = outacc[ct][r];
      }
    }
  }
}

// ======================= FMAM: key-softmax stats ===========================
__global__ __launch_bounds__(256) void fmam_kstats(
    const float* __restrict__ x, const float* __restrict__ fw,
    const float* __restrict__ fb, float* __restrict__ kpart)
{
  __shared__ float xt[64 * 128];
  __shared__ float wl[64 * 65];
  __shared__ float red[4 * 64 * 2];
  const int tid = threadIdx.x;
  const int chunk = blockIdx.x, b = blockIdx.y;
  const float* xb = x + ((size_t)b << 22);
#pragma unroll
  for (int k = 0; k < 16; ++k) {
    int idx = tid + (k << 8); int o = idx >> 6, c = idx & 63;
    wl[o * 65 + c] = fw[idx];
  }
  const int o = tid & 63, ng = tid >> 6;
  const float bias = fb[o];
  float m = -1e30f, s = 0.f;
  for (int st = 0; st < 2; ++st) {
    __syncthreads();
    const int n0 = (chunk << 8) + (st << 7);
#pragma unroll
    for (int k = 0; k < 32; ++k) {
      int idx = tid + (k << 8); int c = idx >> 7, nn = idx & 127;
      xt[idx] = xb[((size_t)c << 16) + (size_t)(n0 + nn)];
    }
    __syncthreads();
    float acc[32];
#pragma unroll
    for (int i = 0; i < 32; ++i) acc[i] = bias;
    const float* wrow = &wl[o * 65];
    for (int c = 0; c < 64; ++c) {
      const float wv = wrow[c];
      const float4* xr = (const float4*)&xt[(c << 7) + (ng << 5)];
#pragma unroll
      for (int q = 0; q < 8; ++q) {
        const float4 xv = xr[q];
        acc[q * 4 + 0] += wv * xv.x; acc[q * 4 + 1] += wv * xv.y;
        acc[q * 4 + 2] += wv * xv.z; acc[q * 4 + 3] += wv * xv.w;
      }
    }
    float lm = acc[0];
#pragma unroll
    for (int i = 1; i < 32; ++i) lm = fmaxf(lm, acc[i]);
    const float nm = fmaxf(m, lm);
    float ls = 0.f;
#pragma unroll
    for (int i = 0; i < 32; ++i) ls += __expf(acc[i] - nm);
    s = s * __expf(m - nm) + ls;
    m = nm;
  }
  __syncthreads();
  red[((ng << 6) + o) * 2] = m; red[((ng << 6) + o) * 2 + 1] = s;
  __syncthreads();
  if (tid < 64) {
    float M = red[tid * 2], S = red[tid * 2 + 1];
#pragma unroll
    for (int g = 1; g < 4; ++g) {
      const float m2 = red[((g << 6) + tid) * 2], s2 = red[((g << 6) + tid) * 2 + 1];
      const float nm = fmaxf(M, m2);
      S = S * __expf(M - nm) + s2 * __expf(m2 - nm);
      M = nm;
    }
    kpart[(((b << 8) + chunk) * 64 + tid) * 2]     = M;
    kpart[(((b << 8) + chunk) * 64 + tid) * 2 + 1] = S;
  }
}

// =================== FMAM: combine per-chunk stats =========================
__global__ void fmam_kreduce(const float* __restrict__ kpart, float* __restrict__ kstats)
{
  const int bo = blockIdx.x;
  const int b = bo >> 6, o = bo & 63;
  const int lane = threadIdx.x;
  float M = -1e30f, S = 0.f;
  for (int ch = lane; ch < 256; ch += 64) {
    const float* pp = kpart + ((size_t)(((b << 8) + ch) * 64 + o)) * 2;
    const float m2 = pp[0], s2 = pp[1];
    const float nm = fmaxf(M, m2);
    S = S * __expf(M - nm) + s2 * __expf(m2 - nm);
    M = nm;
  }
  for (int msk = 1; msk < 64; msk <<= 1) {
    const float m2 = __shfl_xor(M, msk, 64);
    const float s2 = __shfl_xor(S, msk, 64);
    const float nm = fmaxf(M, m2);
    S = S * __expf(M - nm) + s2 * __expf(m2 - nm);
    M = nm;
  }
  if (lane == 0) { kstats[bo * 2] = M; kstats[bo * 2 + 1] = 1.f / S; }
}

// =================== FMAM: ctx partials ====================================
__global__ __launch_bounds__(256) void fmam_ctx(
    const float* __restrict__ x, const float* __restrict__ fw,
    const float* __restrict__ fb, const float* __restrict__ kstats,
    float* __restrict__ ctxpart)
{
  __shared__ float xt[64 * 128];
  __shared__ float wl[64 * 65];
  const int tid = threadIdx.x;
  const int chunk = blockIdx.x, b = blockIdx.y;
  const float* xb = x + ((size_t)b << 22);
#pragma unroll
  for (int k = 0; k < 16; ++k) {
    int idx = tid + (k << 8); int o = idx >> 6, c = idx & 63;
    wl[o * 65 + c] = fw[idx];
  }
  const int o = tid & 63, ng = tid >> 6;
  const float bias = fb[o];
  const float M  = kstats[((b << 6) + o) * 2];
  const float IS = kstats[((b << 6) + o) * 2 + 1];
  float cacc[64];
#pragma unroll
  for (int i = 0; i < 64; ++i) cacc[i] = 0.f;
  for (int st = 0; st < 2; ++st) {
    __syncthreads();
    const int n0 = (chunk << 8) + (st << 7);
#pragma unroll
    for (int k = 0; k < 32; ++k) {
      int idx = tid + (k << 8); int c = idx >> 7, nn = idx & 127;
      xt[idx] = xb[((size_t)c << 16) + (size_t)(n0 + nn)];
    }
    __syncthreads();
    float acc[32];
#pragma unroll
    for (int i = 0; i < 32; ++i) acc[i] = bias;
    const float* wrow = &wl[o * 65];
    for (int c = 0; c < 64; ++c) {
      const float wv = wrow[c];
      const float4* xr = (const float4*)&xt[(c << 7) + (ng << 5)];
#pragma unroll
      for (int q = 0; q < 8; ++q) {
        const float4 xv = xr[q];
        acc[q * 4 + 0] += wv * xv.x; acc[q * 4 + 1] += wv * xv.y;
        acc[q * 4 + 2] += wv * xv.z; acc[q * 4 + 3] += wv * xv.w;
      }
    }
#pragma unroll
    for (int i = 0; i < 32; ++i) acc[i] = __expf(acc[i] - M) * IS;
#pragma unroll
    for (int c = 0; c < 64; ++c) {
      const float4* xr = (const float4*)&xt[(c << 7) + (ng << 5)];
      float s0 = 0.f, s1 = 0.f, s2 = 0.f, s3 = 0.f;
#pragma unroll
      for (int q = 0; q < 8; ++q) {
        const float4 xv = xr[q];
        s0 += xv.x * acc[q * 4 + 0]; s1 += xv.y * acc[q * 4 + 1];
        s2 += xv.z * acc[q * 4 + 2]; s3 += xv.w * acc[q * 4 + 3];
      }
      cacc[c] += (s0 + s1) + (s2 + s3);
    }
  }
  float* red = xt;
#pragma unroll
  for (int cs = 0; cs < 4; ++cs) {
    __syncthreads();
#pragma unroll
    for (int i = 0; i < 16; ++i) red[((ng << 6) + o) * 16 + i] = cacc[(cs << 4) + i];
    __syncthreads();
#pragma unroll
    for (int t = 0; t < 4; ++t) {
      const int v = tid * 4 + t;
      const int o2 = v >> 4, i2 = v & 15;
      const float sum = red[((0 << 6) + o2) * 16 + i2] + red[((1 << 6) + o2) * 16 + i2] +
                        red[((2 << 6) + o2) * 16 + i2] + red[((3 << 6) + o2) * 16 + i2];
      ctxpart[((((size_t)b << 8) + chunk) << 12) + (o2 << 6) + (cs << 4) + i2] = sum;
    }
  }
}

// =================== FMAM: reduce ctx partials =============================
__global__ __launch_bounds__(256) void fmam_ctxreduce(
    const float* __restrict__ ctxpart, float* __restrict__ ctx)
{
  __shared__ float red[256];
  const int bo = blockIdx.x;
  const int b = bo >> 6, o = bo & 63;
  const int tid = threadIdx.x;
  const int c = tid & 63, cg = tid >> 6;
  const float* p = ctxpart + ((size_t)b << 20) + (o << 6) + c;
  float s = 0.f;
  for (int ch = cg * 64; ch < cg * 64 + 64; ++ch) s += p[(size_t)ch << 12];
  red[tid] = s;
  __syncthreads();
  if (tid < 64) {
    const float v = red[tid] + red[tid + 64] + red[tid + 128] + red[tid + 192];
    ctx[((size_t)bo << 6) + tid] = v;
  }
}

// ============ FMAM: queries softmax + freq + final combine =================
__global__ __launch_bounds__(256) void fmam_freq_combine(
    const float* __restrict__ x, const float* __restrict__ qw,
    const float* __restrict__ qb, const float* __restrict__ ctx,
    const float* __restrict__ spa, const float* __restrict__ dw,
    float* __restrict__ out)
{
  extern __shared__ float sm[];
  float* xl   = sm;                 // [64][256]
  float* qwT  = sm + 64 * 256;      // [c][68]
  float* ctxl = qwT + 64 * 68;      // [c][68]
  const int tid = threadIdx.x;
  const int chunk = blockIdx.x, b = blockIdx.y;
  const int n0 = chunk << 8;
  const float* xb = x + ((size_t)b << 22);
#pragma unroll
  for (int k = 0; k < 64; ++k) {
    int idx = tid + (k << 8); int c = idx >> 8, nn = idx & 255;
    xl[idx] = xb[((size_t)c << 16) + (size_t)(n0 + nn)];
  }
#pragma unroll
  for (int k = 0; k < 16; ++k) {
    int idx = tid + (k << 8); int o = idx >> 6, c = idx & 63;
    qwT[c * 68 + o]  = qw[idx];
    ctxl[c * 68 + o] = ctx[(((size_t)b << 6) + o) * 64 + c];
  }
  __syncthreads();

  float4 z4[16];
#pragma unroll
  for (int i = 0; i < 16; ++i) {
    z4[i].x = qb[4 * i]; z4[i].y = qb[4 * i + 1]; z4[i].z = qb[4 * i + 2]; z4[i].w = qb[4 * i + 3];
  }
  for (int c = 0; c < 64; ++c) {
    const float xv = xl[(c << 8) + tid];
    const float4* wr = (const float4*)&qwT[c * 68];
#pragma unroll
    for (int i = 0; i < 16; ++i) {
      const float4 w4 = wr[i];
      z4[i].x += w4.x * xv; z4[i].y += w4.y * xv; z4[i].z += w4.z * xv; z4[i].w += w4.w * xv;
    }
  }
  float zm = z4[0].x;
#pragma unroll
  for (int i = 0; i < 16; ++i)
    zm = fmaxf(zm, fmaxf(fmaxf(z4[i].x, z4[i].y), fmaxf(z4[i].z, z4[i].w)));
  float zs = 0.f;
#pragma unroll
  for (int i = 0; i < 16; ++i) {
    z4[i].x = __expf(z4[i].x - zm); z4[i].y = __expf(z4[i].y - zm);
    z4[i].z = __expf(z4[i].z - zm); z4[i].w = __expf(z4[i].w - zm);
    zs += (z4[i].x + z4[i].y) + (z4[i].z + z4[i].w);
  }
  const float ri = 1.f / zs;
#pragma unroll
  for (int i = 0; i < 16; ++i) {
    xl[((4 * i + 0) << 8) + tid] = z4[i].x * ri;
    xl[((4 * i + 1) << 8) + tid] = z4[i].y * ri;
    xl[((4 * i + 2) << 8) + tid] = z4[i].z * ri;
    xl[((4 * i + 3) << 8) + tid] = z4[i].w * ri;
  }
  float4 f4[16];
#pragma unroll
  for (int i = 0; i < 16; ++i) { f4[i].x = 0.f; f4[i].y = 0.f; f4[i].z = 0.f; f4[i].w = 0.f; }
  for (int c = 0; c < 64; ++c) {
    const float qv = xl[(c << 8) + tid];
    const float4* cr = (const float4*)&ctxl[c * 68];
#pragma unroll
    for (int k = 0; k < 16; ++k) {
      const float4 c4 = cr[k];
      f4[k].x += c4.x * qv; f4[k].y += c4.y * qv; f4[k].z += c4.z * qv; f4[k].w += c4.w * qv;
    }
  }
  const size_t base = ((size_t)b << 22) + (size_t)(n0 + tid);
#pragma unroll
  for (int i = 0; i < 16; ++i) {
#pragma unroll
    for (int j = 0; j < 4; ++j) {
      const int k = 4 * i + j;
      const float d0 = dw[k * 2], d1 = dw[k * 2 + 1];
      const float fv = (j == 0) ? f4[i].x : (j == 1) ? f4[i].y : (j == 2) ? f4[i].z : f4[i].w;
      const size_t a = base + ((size_t)k << 16);
      out[a] = spa[a] * d0 + fv * d1;
    }
  }
}

// ===========================================================================
extern "C" void kernel_launch(void* const* d_in, const int* in_sizes, int n_in,
                              void* d_out, int out_size, void* d_ws, size_t ws_size,
                              hipStream_t stream) {
  const float* x  = (const float*)d_in[0];
  const float* Wq = (const float*)d_in[1];
  const float* Wk = (const float*)d_in[2];
  const float* Wv = (const float*)d_in[3];
  const float* Wo = (const float*)d_in[4];
  const float* qw = (const float*)d_in[7];
  const float* qb = (const float*)d_in[8];
  const float* fw = (const float*)d_in[9];
  const float* fb = (const float*)d_in[10];
  const float* dw = (const float*)d_in[11];
  float* out = (float*)d_out;

  float* ws = (float*)d_ws;
  float* spa     = ws;                       // 8388608 f
  float* kpart   = spa + 8388608;            // 65536 f (also hosts Wt3/WoTp early)
  float* kstats  = kpart + 65536;            // 256 f
  float* ctxpart = kstats + 256;             // 2097152 f
  float* ctx     = ctxpart + 2097152;        // 8192 f

  // bf16 W buffers live in the kpart region: prep_w -> attn_mfma use them,
  // then fmam_kstats (later in stream order) overwrites kpart. 53248 shorts
  // = 104 KiB <= kpart's 256 KiB.
  short* Wt3  = (short*)kpart;               // [3][192][64]
  short* WoTp = Wt3 + 36864;                 // [4][64][64]

  const size_t attn_lds = 38912;
  const size_t f5_lds   = (size_t)(64 * 256 + 2 * 64 * 68) * sizeof(float);
  (void)hipFuncSetAttribute((const void*)attn_mfma,
                            hipFuncAttributeMaxDynamicSharedMemorySize, (int)attn_lds);
  (void)hipFuncSetAttribute((const void*)fmam_freq_combine,
                            hipFuncAttributeMaxDynamicSharedMemorySize, (int)f5_lds);

  hipLaunchKernelGGL(prep_w, dim3(144), dim3(256), 0, stream, Wq, Wk, Wv, Wo, Wt3, WoTp);
  hipLaunchKernelGGL(attn_mfma, dim3(2048), dim3(256), attn_lds, stream, x, Wt3, WoTp, spa);
  hipLaunchKernelGGL(fmam_kstats, dim3(256, 2), dim3(256), 0, stream, x, fw, fb, kpart);
  hipLaunchKernelGGL(fmam_kreduce, dim3(128), dim3(64), 0, stream, kpart, kstats);
  hipLaunchKernelGGL(fmam_ctx, dim3(256, 2), dim3(256), 0, stream, x, fw, fb, kstats, ctxpart);
  hipLaunchKernelGGL(fmam_ctxreduce, dim3(128), dim3(256), 0, stream, ctxpart, ctx);
  hipLaunchKernelGGL(fmam_freq_combine, dim3(256, 2), dim3(256), f5_lds, stream,
                     x, qw, qb, ctx, spa, dw, out);
}

// Round 3
// 183.246 us; speedup vs baseline: 4.1458x; 2.0075x over previous
//
#include <hip/hip_runtime.h>
#include <hip/hip_bf16.h>

// ---------------------------------------------------------------------------
// FPSAttn: LSH/permutation machinery is a mathematical no-op (full attention
// over the permuted 64-token patch, un-permuted after; both rounds identical,
// probs==0.5). Compute:
//   spa  = patchwise 4-head softmax attention (64 tok, d=48) + Wo projection
//   freq = FMAM global-context module  (now fully MFMA-based)
//   out  = spa*dw[:,0] + freq*dw[:,1]
// MFMA frag conventions (verified in round 1's attn kernel):
//   A-frag: lane holds A[row=l&15][k = (l>>4)*8 + j] (+32 per ks)
//   B-frag: lane holds B[k][col=l&15], same k layout
//   C-frag: col = l&15, row = (l>>4)*4 + r
// ---------------------------------------------------------------------------

typedef __attribute__((ext_vector_type(8))) short bf16x8;   // 8 bf16 (4 VGPRs)
typedef __attribute__((ext_vector_type(4))) float f32x4;

static __device__ __forceinline__ short f2bf(float f) {
  __hip_bfloat16 h = __float2bfloat16(f);   // RNE
  return *reinterpret_cast<short*>(&h);
}
static __device__ __forceinline__ float bf2f(short s) {
  unsigned int u = ((unsigned int)(unsigned short)s) << 16;
  return __uint_as_float(u);
}

// swizzled byte offset into a [rows][64] bf16 LDS tile (128B rows)
#define LSWZ(row, bytecol) ((((row) << 7) + (bytecol)) ^ (((row) & 7) << 4))

// Build an MFMA frag from x[c][n]-major global: lane supplies x[c0+j][n],
// j=0..7 (K=c contiguous). Per instr: 16 lanes consecutive n -> 64B runs.
static __device__ __forceinline__ bf16x8 load_xfrag(const float* xg, int c0, int n) {
  bf16x8 r;
#pragma unroll
  for (int j = 0; j < 8; ++j) r[j] = f2bf(xg[((size_t)(c0 + j) << 16) + (size_t)n]);
  return r;
}

// ======================= W prep: transpose + bf16 ==========================
__global__ __launch_bounds__(256) void prep_w(
    const float* __restrict__ Wq, const float* __restrict__ Wk,
    const float* __restrict__ Wv, const float* __restrict__ Wo,
    const float* __restrict__ fw, const float* __restrict__ qw,
    short* __restrict__ Wt3, short* __restrict__ WoTp,
    short* __restrict__ fwb, short* __restrict__ qwb)
{
  int i = blockIdx.x * 256 + threadIdx.x;
  if (i < 36864) {
    int m = i / 12288;
    int r = (i % 12288) >> 6;       // dim 0..191
    int c = i & 63;
    const float* W = (m == 0) ? Wq : (m == 1) ? Wk : Wv;
    Wt3[i] = f2bf(W[c * 192 + r]);
  }
  if (i < 16384) {
    int h = i >> 12, co = (i >> 6) & 63, j = i & 63;
    WoTp[i] = (j < 48) ? f2bf(Wo[(h * 48 + j) * 64 + co]) : (short)0;
  }
  if (i < 4096) {
    fwb[i] = f2bf(fw[i]);   // fmam_w [o][c] native
    qwb[i] = f2bf(qw[i]);   // q_w    [o][c] native
  }
}

// ======================= Patch attention (MFMA) ============================
__global__ __launch_bounds__(256, 4) void attn_mfma(
    const float* __restrict__ x, const short* __restrict__ Wt3,
    const short* __restrict__ WoTp, float* __restrict__ spa)
{
  extern __shared__ char lds[];
  char* xb_ = lds;
  char* qb_ = lds + 8192;
  char* kb_ = lds + 16384;
  char* vb_ = lds + 24576;   // 48 rows
  char* pb_ = lds + 30720;   // total 38912 B

  const int tid  = threadIdx.x;
  const int lane = tid & 63;
  const int w    = tid >> 6;
  const int l15  = lane & 15;
  const int l4   = lane >> 4;

  const int pid  = blockIdx.x;
  const int b    = pid >> 10;
  const int prem = pid & 1023;
  const int y0   = (prem >> 5) << 3;
  const int x0   = (prem & 31) << 3;
  const float* xg = x + ((size_t)b << 22);

#pragma unroll
  for (int k = 0; k < 16; ++k) {
    int idx = tid + (k << 8);
    int c = idx >> 6, t = idx & 63;
    float v = xg[((size_t)c << 16) + (size_t)((y0 + (t >> 3)) * 256 + x0 + (t & 7))];
    *(short*)(xb_ + LSWZ(t, c * 2)) = f2bf(v);
  }
#pragma unroll
  for (int i = 0; i < 2; ++i) {
    int idx = tid + (i << 8);
    int row = idx >> 3, dw = idx & 7;
    *(int*)(qb_ + LSWZ(row, 96 + dw * 4)) = 0;
    *(int*)(kb_ + LSWZ(row, 96 + dw * 4)) = 0;
  }
  __syncthreads();

  f32x4 outacc[4];
#pragma unroll
  for (int i = 0; i < 4; ++i) outacc[i] = (f32x4)0.f;

  for (int h = 0; h < 4; ++h) {
    {
      bf16x8 xf[2];
#pragma unroll
      for (int ks = 0; ks < 2; ++ks)
        xf[ks] = *(const bf16x8*)(xb_ + LSWZ(l15 + 16 * w, 16 * l4 + 64 * ks));
#pragma unroll
      for (int m = 0; m < 2; ++m) {
        const short* WT = Wt3 + m * 12288;
        char* dst = m ? kb_ : qb_;
#pragma unroll
        for (int ct = 0; ct < 3; ++ct) {
          f32x4 acc = (f32x4)0.f;
          const int dimrow = l15 + 16 * (h * 3 + ct);
#pragma unroll
          for (int ks = 0; ks < 2; ++ks) {
            bf16x8 bf = *(const bf16x8*)(WT + dimrow * 64 + 8 * l4 + 32 * ks);
            acc = __builtin_amdgcn_mfma_f32_16x16x32_bf16(xf[ks], bf, acc, 0, 0, 0);
          }
#pragma unroll
          for (int r = 0; r < 4; ++r)
            *(short*)(dst + LSWZ(16 * w + 4 * l4 + r, (16 * ct + l15) * 2)) = f2bf(acc[r]);
        }
      }
#pragma unroll
      for (int rt = 0; rt < 3; ++rt) {
        f32x4 acc = (f32x4)0.f;
        const int dimrow = l15 + 16 * (h * 3 + rt);
#pragma unroll
        for (int ks = 0; ks < 2; ++ks) {
          bf16x8 af = *(const bf16x8*)(Wt3 + 2 * 12288 + dimrow * 64 + 8 * l4 + 32 * ks);
          acc = __builtin_amdgcn_mfma_f32_16x16x32_bf16(af, xf[ks], acc, 0, 0, 0);
        }
#pragma unroll
        for (int r = 0; r < 4; ++r)
          *(short*)(vb_ + LSWZ(16 * rt + 4 * l4 + r, (16 * w + l15) * 2)) = f2bf(acc[r]);
      }
    }
    __syncthreads();
    {
      bf16x8 qf[2];
#pragma unroll
      for (int ks = 0; ks < 2; ++ks)
        qf[ks] = *(const bf16x8*)(qb_ + LSWZ(l15 + 16 * w, 16 * l4 + 64 * ks));
      f32x4 s[4];
#pragma unroll
      for (int ct = 0; ct < 4; ++ct) {
        f32x4 acc = (f32x4)0.f;
#pragma unroll
        for (int ks = 0; ks < 2; ++ks) {
          bf16x8 kf = *(const bf16x8*)(kb_ + LSWZ(l15 + 16 * ct, 16 * l4 + 64 * ks));
          acc = __builtin_amdgcn_mfma_f32_16x16x32_bf16(qf[ks], kf, acc, 0, 0, 0);
        }
        s[ct] = acc;
      }
#pragma unroll
      for (int r = 0; r < 4; ++r) {
        float m = fmaxf(fmaxf(s[0][r], s[1][r]), fmaxf(s[2][r], s[3][r]));
        for (int msk = 1; msk <= 8; msk <<= 1) m = fmaxf(m, __shfl_xor(m, msk, 64));
        float e0 = __expf(s[0][r] - m), e1 = __expf(s[1][r] - m);
        float e2 = __expf(s[2][r] - m), e3 = __expf(s[3][r] - m);
        float sum = (e0 + e1) + (e2 + e3);
        for (int msk = 1; msk <= 8; msk <<= 1) sum += __shfl_xor(sum, msk, 64);
        const float ri = 1.f / sum;
        const int row = 16 * w + 4 * l4 + r;
        *(short*)(pb_ + LSWZ(row, (l15) * 2))      = f2bf(e0 * ri);
        *(short*)(pb_ + LSWZ(row, (l15 + 16) * 2)) = f2bf(e1 * ri);
        *(short*)(pb_ + LSWZ(row, (l15 + 32) * 2)) = f2bf(e2 * ri);
        *(short*)(pb_ + LSWZ(row, (l15 + 48) * 2)) = f2bf(e3 * ri);
      }
    }
    __syncthreads();
    {
      bf16x8 pf[2];
#pragma unroll
      for (int ks = 0; ks < 2; ++ks)
        pf[ks] = *(const bf16x8*)(pb_ + LSWZ(l15 + 16 * w, 16 * l4 + 64 * ks));
#pragma unroll
      for (int rt = 0; rt < 3; ++rt) {
        f32x4 acc = (f32x4)0.f;
#pragma unroll
        for (int ks = 0; ks < 2; ++ks) {
          bf16x8 vf = *(const bf16x8*)(vb_ + LSWZ(l15 + 16 * rt, 16 * l4 + 64 * ks));
          acc = __builtin_amdgcn_mfma_f32_16x16x32_bf16(vf, pf[ks], acc, 0, 0, 0);
        }
#pragma unroll
        for (int r = 0; r < 4; ++r)
          *(short*)(qb_ + LSWZ(16 * w + l15, (16 * rt + 4 * l4 + r) * 2)) = f2bf(acc[r]);
      }
    }
    __syncthreads();
    {
#pragma unroll
      for (int ks = 0; ks < 2; ++ks) {
        bf16x8 af = *(const bf16x8*)(WoTp + (h << 12) + (l15 + 16 * w) * 64 + 8 * l4 + 32 * ks);
#pragma unroll
        for (int ct = 0; ct < 4; ++ct) {
          bf16x8 of = *(const bf16x8*)(qb_ + LSWZ(l15 + 16 * ct, 16 * l4 + 64 * ks));
          outacc[ct] = __builtin_amdgcn_mfma_f32_16x16x32_bf16(af, of, outacc[ct], 0, 0, 0);
        }
      }
    }
    __syncthreads();
  }
  {
    float* sb = spa + ((size_t)b << 22);
#pragma unroll
    for (int ct = 0; ct < 4; ++ct) {
      const int t = 16 * ct + l15;
      const size_t base = (size_t)((y0 + (t >> 3)) * 256 + x0 + (t & 7));
#pragma unroll
      for (int r = 0; r < 4; ++r) {
        const int co = 16 * w + 4 * l4 + r;
        sb[((size_t)co << 16) + base] = outacc[ct][r];
      }
    }
  }
}

// =================== FMAM K1: Y = fw@x + fb (MFMA) =========================
// Stores Y bf16 [b][o][n]; per-(b,chunk,o) online max/sumexp -> kpart.
// LDS-free operands: fw frags resident, x frags via transpose-free global reads.
__global__ __launch_bounds__(256) void fmam_y(
    const float* __restrict__ x, const short* __restrict__ fwb,
    const float* __restrict__ fb, short* __restrict__ Y,
    float* __restrict__ kpart)
{
  __shared__ float red[4 * 64 * 2];
  const int tid = threadIdx.x, lane = tid & 63, w = tid >> 6;
  const int l15 = lane & 15, l4 = lane >> 4;
  const int chunk = blockIdx.x, b = blockIdx.y;
  const float* xg = x + ((size_t)b << 22);
  short* yg = Y + ((size_t)b << 22);
  const int n0 = (chunk << 8) + (w << 6);   // wave n-strip of 64

  bf16x8 af[4][2];
#pragma unroll
  for (int ot = 0; ot < 4; ++ot)
#pragma unroll
    for (int ks = 0; ks < 2; ++ks)
      af[ot][ks] = *(const bf16x8*)(fwb + (ot * 16 + l15) * 64 + ks * 32 + l4 * 8);
  float4 fbv[4];
#pragma unroll
  for (int ot = 0; ot < 4; ++ot) fbv[ot] = *(const float4*)(fb + ot * 16 + l4 * 4);

  float m_l[16], s_l[16];
#pragma unroll
  for (int i = 0; i < 16; ++i) { m_l[i] = -1e30f; s_l[i] = 0.f; }

#pragma unroll
  for (int nt = 0; nt < 4; ++nt) {
    const int n = n0 + nt * 16 + l15;
    bf16x8 bf0 = load_xfrag(xg, l4 * 8, n);
    bf16x8 bf1 = load_xfrag(xg, 32 + l4 * 8, n);
#pragma unroll
    for (int ot = 0; ot < 4; ++ot) {
      f32x4 acc;
      acc[0] = fbv[ot].x; acc[1] = fbv[ot].y; acc[2] = fbv[ot].z; acc[3] = fbv[ot].w;
      acc = __builtin_amdgcn_mfma_f32_16x16x32_bf16(af[ot][0], bf0, acc, 0, 0, 0);
      acc = __builtin_amdgcn_mfma_f32_16x16x32_bf16(af[ot][1], bf1, acc, 0, 0, 0);
#pragma unroll
      for (int r = 0; r < 4; ++r) {
        short yb = f2bf(acc[r]);
        yg[((size_t)(ot * 16 + l4 * 4 + r) << 16) + (size_t)n] = yb;
        float yr = bf2f(yb);                  // stats on rounded value (consistent w/ K3)
        const int i = ot * 4 + r;
        float nm = fmaxf(m_l[i], yr);
        s_l[i] = s_l[i] * __expf(m_l[i] - nm) + __expf(yr - nm);
        m_l[i] = nm;
      }
    }
  }
  // merge over the 16 lanes (l&15) sharing each o-row
#pragma unroll
  for (int i = 0; i < 16; ++i) {
#pragma unroll
    for (int msk = 1; msk <= 8; msk <<= 1) {
      float om = __shfl_xor(m_l[i], msk, 64);
      float os = __shfl_xor(s_l[i], msk, 64);
      float nm = fmaxf(m_l[i], om);
      s_l[i] = s_l[i] * __expf(m_l[i] - nm) + os * __expf(om - nm);
      m_l[i] = nm;
    }
  }
  if (l15 == 0) {
#pragma unroll
    for (int ot = 0; ot < 4; ++ot)
#pragma unroll
      for (int r = 0; r < 4; ++r) {
        const int o = ot * 16 + l4 * 4 + r;
        red[(w * 64 + o) * 2]     = m_l[ot * 4 + r];
        red[(w * 64 + o) * 2 + 1] = s_l[ot * 4 + r];
      }
  }
  __syncthreads();
  if (tid < 64) {
    float M = red[tid * 2], S = red[tid * 2 + 1];
#pragma unroll
    for (int g = 1; g < 4; ++g) {
      const float m2 = red[((g << 6) + tid) * 2], s2 = red[((g << 6) + tid) * 2 + 1];
      const float nm = fmaxf(M, m2);
      S = S * __expf(M - nm) + s2 * __expf(m2 - nm);
      M = nm;
    }
    kpart[(((b << 8) + chunk) * 64 + tid) * 2]     = M;
    kpart[(((b << 8) + chunk) * 64 + tid) * 2 + 1] = S;
  }
}

// =================== FMAM: combine per-chunk stats =========================
__global__ void fmam_kreduce(const float* __restrict__ kpart, float* __restrict__ kstats)
{
  const int bo = blockIdx.x;
  const int b = bo >> 6, o = bo & 63;
  const int lane = threadIdx.x;
  float M = -1e30f, S = 0.f;
  for (int ch = lane; ch < 256; ch += 64) {
    const float* pp = kpart + ((size_t)(((b << 8) + ch) * 64 + o)) * 2;
    const float m2 = pp[0], s2 = pp[1];
    const float nm = fmaxf(M, m2);
    S = S * __expf(M - nm) + s2 * __expf(m2 - nm);
    M = nm;
  }
  for (int msk = 1; msk < 64; msk <<= 1) {
    const float m2 = __shfl_xor(M, msk, 64);
    const float s2 = __shfl_xor(S, msk, 64);
    const float nm = fmaxf(M, m2);
    S = S * __expf(M - nm) + s2 * __expf(m2 - nm);
    M = nm;
  }
  if (lane == 0) { kstats[bo * 2] = M; kstats[bo * 2 + 1] = 1.f / S; }
}

// =================== FMAM K3: ctx partials via MFMA ========================
// ctxpart[b][chunk][o][c] = sum_{n in chunk} p[o][n] x[c][n],
// p built in-register from bf16 Y. A = p[o][n-K], B = x[c-col][n-K]. LDS-free.
__global__ __launch_bounds__(256) void fmam_ctx_mfma(
    const float* __restrict__ x, const short* __restrict__ Y,
    const float* __restrict__ kstats, float* __restrict__ ctxpart)
{
  const int tid = threadIdx.x, lane = tid & 63, w = tid >> 6;  // w = c-tile
  const int l15 = lane & 15, l4 = lane >> 4;
  const int chunk = blockIdx.x, b = blockIdx.y;
  const float* xg = x + ((size_t)b << 22);
  const short* yg = Y + ((size_t)b << 22);
  const int n0 = chunk << 8;

  float M[4], IS[4];
#pragma unroll
  for (int ot = 0; ot < 4; ++ot) {
    const int o = ot * 16 + l15;
    M[ot]  = kstats[((b << 6) + o) * 2];
    IS[ot] = kstats[((b << 6) + o) * 2 + 1];
  }
  f32x4 acc[4];
#pragma unroll
  for (int i = 0; i < 4; ++i) acc[i] = (f32x4)0.f;

#pragma unroll
  for (int ks = 0; ks < 8; ++ks) {
    const int nk = n0 + ks * 32 + l4 * 8;
    // B-frag: x[c = w*16+l15][nk..nk+7]
    const float* xr = xg + ((size_t)(w * 16 + l15) << 16) + nk;
    const float4 xa = *(const float4*)xr;
    const float4 xb2 = *(const float4*)(xr + 4);
    bf16x8 bfr;
    bfr[0] = f2bf(xa.x); bfr[1] = f2bf(xa.y); bfr[2] = f2bf(xa.z); bfr[3] = f2bf(xa.w);
    bfr[4] = f2bf(xb2.x); bfr[5] = f2bf(xb2.y); bfr[6] = f2bf(xb2.z); bfr[7] = f2bf(xb2.w);
#pragma unroll
    for (int ot = 0; ot < 4; ++ot) {
      bf16x8 ya = *(const bf16x8*)(yg + ((size_t)(ot * 16 + l15) << 16) + nk);
      bf16x8 pa;
#pragma unroll
      for (int j = 0; j < 8; ++j)
        pa[j] = f2bf(__expf(bf2f(ya[j]) - M[ot]) * IS[ot]);
      acc[ot] = __builtin_amdgcn_mfma_f32_16x16x32_bf16(pa, bfr, acc[ot], 0, 0, 0);
    }
  }
  float* cp = ctxpart + ((((size_t)b << 8) + chunk) << 12);
#pragma unroll
  for (int ot = 0; ot < 4; ++ot)
#pragma unroll
    for (int r = 0; r < 4; ++r)
      cp[(ot * 16 + l4 * 4 + r) * 64 + w * 16 + l15] = acc[ot][r];
}

// =================== FMAM: reduce ctx partials =============================
__global__ __launch_bounds__(256) void fmam_ctxreduce(
    const float* __restrict__ ctxpart, float* __restrict__ ctx)
{
  __shared__ float red[256];
  const int bo = blockIdx.x;
  const int b = bo >> 6, o = bo & 63;
  const int tid = threadIdx.x;
  const int c = tid & 63, cg = tid >> 6;
  const float* p = ctxpart + ((size_t)b << 20) + (o << 6) + c;
  float s = 0.f;
  for (int ch = cg * 64; ch < cg * 64 + 64; ++ch) s += p[(size_t)ch << 12];
  red[tid] = s;
  __syncthreads();
  if (tid < 64) {
    const float v = red[tid] + red[tid + 64] + red[tid + 128] + red[tid + 192];
    ctx[((size_t)bo << 6) + tid] = v;    // ctx_g[b][o][c] = ref-ctx[b,c,o]
  }
}

// ========== FMAM K4: z -> softmax(o) -> freq = ctx@q -> combine ============
// Block = 128 positions (4 waves x 32). z via MFMA D[n][o]; softmax over o by
// 4 in-lane + 4 shfl_xor; q bounced through swizzled LDS; freq via MFMA.
__global__ __launch_bounds__(256) void freq_combine(
    const float* __restrict__ x, const short* __restrict__ qwb,
    const float* __restrict__ qb, const float* __restrict__ ctx,
    const float* __restrict__ spa, const float* __restrict__ dw,
    float* __restrict__ out)
{
  __shared__ short ctxb[64 * 64];   // [k][c] bf16, LSWZ rows
  __shared__ short q_l[128 * 64];   // [n][o] bf16, LSWZ rows
  const int tid = threadIdx.x, lane = tid & 63, w = tid >> 6;
  const int l15 = lane & 15, l4 = lane >> 4;
  const int chunk = blockIdx.x, b = blockIdx.y;
  const int n0 = chunk << 7;
  const float* xg = x + ((size_t)b << 22);

#pragma unroll
  for (int k = 0; k < 16; ++k) {
    int idx = tid + (k << 8); int row = idx >> 6, col = idx & 63;
    float v = ctx[(((size_t)b << 6) + row) * 64 + col];
    *(short*)((char*)ctxb + LSWZ(row, col * 2)) = f2bf(v);
  }

  const int nw = w << 5;   // wave n-base within chunk
  bf16x8 qwf[4][2];
#pragma unroll
  for (int ot = 0; ot < 4; ++ot)
#pragma unroll
    for (int ks = 0; ks < 2; ++ks)
      qwf[ot][ks] = *(const bf16x8*)(qwb + (ot * 16 + l15) * 64 + ks * 32 + l4 * 8);
  float qbv[4];
#pragma unroll
  for (int ot = 0; ot < 4; ++ot) qbv[ot] = qb[ot * 16 + l15];

  f32x4 zacc[2][4];
#pragma unroll
  for (int nt = 0; nt < 2; ++nt) {
    const int n = n0 + nw + nt * 16 + l15;
    bf16x8 a0 = load_xfrag(xg, l4 * 8, n);
    bf16x8 a1 = load_xfrag(xg, 32 + l4 * 8, n);
#pragma unroll
    for (int ot = 0; ot < 4; ++ot) {
      f32x4 acc = (f32x4)(qbv[ot]);
      acc = __builtin_amdgcn_mfma_f32_16x16x32_bf16(a0, qwf[ot][0], acc, 0, 0, 0);
      acc = __builtin_amdgcn_mfma_f32_16x16x32_bf16(a1, qwf[ot][1], acc, 0, 0, 0);
      zacc[nt][ot] = acc;
    }
  }
  __syncthreads();   // ctxb staged; also pre-q_l-write sync
  // softmax over o (64 = 4 in-lane x 16 lanes)
#pragma unroll
  for (int nt = 0; nt < 2; ++nt)
#pragma unroll
    for (int r = 0; r < 4; ++r) {
      float v0 = zacc[nt][0][r], v1 = zacc[nt][1][r];
      float v2 = zacc[nt][2][r], v3 = zacc[nt][3][r];
      float m = fmaxf(fmaxf(v0, v1), fmaxf(v2, v3));
      for (int msk = 1; msk <= 8; msk <<= 1) m = fmaxf(m, __shfl_xor(m, msk, 64));
      float e0 = __expf(v0 - m), e1 = __expf(v1 - m);
      float e2 = __expf(v2 - m), e3 = __expf(v3 - m);
      float s = (e0 + e1) + (e2 + e3);
      for (int msk = 1; msk <= 8; msk <<= 1) s += __shfl_xor(s, msk, 64);
      const float inv = 1.f / s;
      const int row = nw + nt * 16 + l4 * 4 + r;
      *(short*)((char*)q_l + LSWZ(row, (l15) * 2))      = f2bf(e0 * inv);
      *(short*)((char*)q_l + LSWZ(row, (l15 + 16) * 2)) = f2bf(e1 * inv);
      *(short*)((char*)q_l + LSWZ(row, (l15 + 32) * 2)) = f2bf(e2 * inv);
      *(short*)((char*)q_l + LSWZ(row, (l15 + 48) * 2)) = f2bf(e3 * inv);
    }
  __syncthreads();
  // freq = ctx @ q ; epilogue
#pragma unroll
  for (int nt = 0; nt < 2; ++nt) {
    bf16x8 qf[2];
#pragma unroll
    for (int ks = 0; ks < 2; ++ks)
      qf[ks] = *(const bf16x8*)((char*)q_l + LSWZ(nw + nt * 16 + l15, (ks * 32 + l4 * 8) * 2));
    const int n = n0 + nw + nt * 16 + l15;
#pragma unroll
    for (int kt = 0; kt < 4; ++kt) {
      f32x4 facc = (f32x4)0.f;
#pragma unroll
      for (int ks = 0; ks < 2; ++ks) {
        bf16x8 cf = *(const bf16x8*)((char*)ctxb + LSWZ(kt * 16 + l15, (ks * 32 + l4 * 8) * 2));
        facc = __builtin_amdgcn_mfma_f32_16x16x32_bf16(cf, qf[ks], facc, 0, 0, 0);
      }
#pragma unroll
      for (int r = 0; r < 4; ++r) {
        const int kc = kt * 16 + l4 * 4 + r;
        const size_t a = ((size_t)b << 22) + ((size_t)kc << 16) + (size_t)n;
        out[a] = spa[a] * dw[kc * 2] + facc[r] * dw[kc * 2 + 1];
      }
    }
  }
}

// ===========================================================================
extern "C" void kernel_launch(void* const* d_in, const int* in_sizes, int n_in,
                              void* d_out, int out_size, void* d_ws, size_t ws_size,
                              hipStream_t stream) {
  const float* x  = (const float*)d_in[0];
  const float* Wq = (const float*)d_in[1];
  const float* Wk = (const float*)d_in[2];
  const float* Wv = (const float*)d_in[3];
  const float* Wo = (const float*)d_in[4];
  const float* qw = (const float*)d_in[7];
  const float* qb = (const float*)d_in[8];
  const float* fw = (const float*)d_in[9];
  const float* fb = (const float*)d_in[10];
  const float* dw = (const float*)d_in[11];
  float* out = (float*)d_out;

  float* ws = (float*)d_ws;
  float* spa     = ws;                       // 8388608 f (32MB)
  float* kpart   = spa + 8388608;            // 65536 f
  float* kstats  = kpart + 65536;            // 256 f
  float* ctxpart = kstats + 256;             // 2097152 f (8MB)
  float* ctx     = ctxpart + 2097152;        // 8192 f
  short* wbuf    = (short*)(ctx + 8192);     // 61440 shorts (120KB)

  short* Wt3  = wbuf;                        // [3][192][64]
  short* WoTp = Wt3 + 36864;                 // [4][64][64]
  short* fwb  = WoTp + 16384;                // [64][64]
  short* qwb  = fwb + 4096;                  // [64][64]

  // Y bf16 [2][64][65536] = 16MB lives in the spa region: written by fmam_y,
  // consumed by fmam_ctx_mfma, then attn_mfma overwrites the region with spa
  // (stream-ordered; Y is dead by then).
  short* Y = (short*)spa;

  const size_t attn_lds = 38912;
  (void)hipFuncSetAttribute((const void*)attn_mfma,
                            hipFuncAttributeMaxDynamicSharedMemorySize, (int)attn_lds);

  hipLaunchKernelGGL(prep_w, dim3(144), dim3(256), 0, stream,
                     Wq, Wk, Wv, Wo, fw, qw, Wt3, WoTp, fwb, qwb);
  hipLaunchKernelGGL(fmam_y, dim3(256, 2), dim3(256), 0, stream, x, fwb, fb, Y, kpart);
  hipLaunchKernelGGL(fmam_kreduce, dim3(128), dim3(64), 0, stream, kpart, kstats);
  hipLaunchKernelGGL(fmam_ctx_mfma, dim3(256, 2), dim3(256), 0, stream, x, Y, kstats, ctxpart);
  hipLaunchKernelGGL(fmam_ctxreduce, dim3(128), dim3(256), 0, stream, ctxpart, ctx);
  hipLaunchKernelGGL(attn_mfma, dim3(2048), dim3(256), attn_lds, stream, x, Wt3, WoTp, spa);
  hipLaunchKernelGGL(freq_combine, dim3(512, 2), dim3(256), 0, stream,
                     x, qwb, qb, ctx, spa, dw, out);
}

// Round 5
// 136.029 us; speedup vs baseline: 5.5849x; 1.3471x over previous
//
#include <hip/hip_runtime.h>
#include <hip/hip_bf16.h>

// ---------------------------------------------------------------------------
// FPSAttn. LSH machinery is a no-op (full attention over the permuted patch,
// inverse-permuted; rounds identical, probs==0.5).
//   out = spa*dw0 + freq*dw1
//   spa  = patch 4-head attention + Wo   (fused kernel, wave-per-head)
//   freq = FMAM: ctx from key-softmax (MFMA kernels) + queries-softmax fused
//          into the attention kernel epilogue.
// MFMA frag conventions (verified rounds 1-3):
//   A-frag: lane(l15,l4) holds A[16*rt + l15][32*ks + 8*l4 + j], j=0..7
//   B-frag: lane holds B[32*ks + 8*l4 + j][16*ct + l15]
//   C-frag: lane holds C[16*rt + 4*l4 + r][16*ct + l15], r=0..3
// Repack identity: a C-frag of Z (row-dim R, col-dim Q) provides the A/B-frag
// of Z-as-[k=R][l15=Q] via same-l15 lane permutation:
//   srcLane(j<4) = l15 + 32*(l4&1); srcLane(j>=4) = +16; r = j&3;
//   tile = L for dest l4 in {0,1}, H for {2,3}. (Robust to any k-slot map:
//   both MFMA operands use the same bijection.)
// NOTE: bf16 packing is PURE C++ (no inline-asm cvt_pk) per guide T12/m240.
// ---------------------------------------------------------------------------

typedef __attribute__((ext_vector_type(8))) short bf16x8;
typedef __attribute__((ext_vector_type(4))) float f32x4;
typedef __attribute__((ext_vector_type(4))) unsigned u32x4;

static __device__ __forceinline__ short f2bf(float f) {
  __hip_bfloat16 h = __float2bfloat16(f);
  return *reinterpret_cast<short*>(&h);
}
static __device__ __forceinline__ float bf2f(short s) {
  return __uint_as_float(((unsigned)(unsigned short)s) << 16);
}
// pack two f32 -> one u32 of 2 bf16 (low = a, high = b). Pure C++ (m240).
static __device__ __forceinline__ unsigned pack2bf(float a, float b) {
  return (unsigned)(unsigned short)f2bf(a) | ((unsigned)(unsigned short)f2bf(b) << 16);
}
static __device__ __forceinline__ f32x4 MFMA(bf16x8 a, bf16x8 b, f32x4 c) {
  return __builtin_amdgcn_mfma_f32_16x16x32_bf16(a, b, c, 0, 0, 0);
}

// swizzled byte offset into a [rows][64] bf16 LDS tile (128B rows)
#define LSWZ(row, bytecol) ((((row) << 7) + (bytecol)) ^ (((row) & 7) << 4))

// Repack two packed C-frag tiles (L = slab rows [0,16), H = rows [16,32))
// into an MFMA A/B-frag. pl0/pl1 = pack2bf(acc0,acc1)/(acc2,acc3).
static __device__ __forceinline__ bf16x8 repack(
    unsigned pl0, unsigned pl1, unsigned ph0, unsigned ph1,
    int srcA, int srcB, bool hi) {
  unsigned l0 = __shfl((int)pl0, srcA, 64), l1 = __shfl((int)pl1, srcA, 64);
  unsigned l2 = __shfl((int)pl0, srcB, 64), l3 = __shfl((int)pl1, srcB, 64);
  unsigned h0 = __shfl((int)ph0, srcA, 64), h1 = __shfl((int)ph1, srcA, 64);
  unsigned h2 = __shfl((int)ph0, srcB, 64), h3 = __shfl((int)ph1, srcB, 64);
  u32x4 v;
  v[0] = hi ? h0 : l0; v[1] = hi ? h1 : l1;
  v[2] = hi ? h2 : l2; v[3] = hi ? h3 : l3;
  return __builtin_bit_cast(bf16x8, v);
}
// variant: H tile is all-zero (K-padding)
static __device__ __forceinline__ bf16x8 repack1(
    unsigned pl0, unsigned pl1, int srcA, int srcB, bool hi) {
  unsigned l0 = __shfl((int)pl0, srcA, 64), l1 = __shfl((int)pl1, srcA, 64);
  unsigned l2 = __shfl((int)pl0, srcB, 64), l3 = __shfl((int)pl1, srcB, 64);
  u32x4 v;
  v[0] = hi ? 0u : l0; v[1] = hi ? 0u : l1;
  v[2] = hi ? 0u : l2; v[3] = hi ? 0u : l3;
  return __builtin_bit_cast(bf16x8, v);
}

// frag of x from global [c][n]: lane supplies x[c0+j][n]
static __device__ __forceinline__ bf16x8 load_xfrag(const float* xg, int c0, int n) {
  bf16x8 r;
#pragma unroll
  for (int j = 0; j < 8; ++j) r[j] = f2bf(xg[((size_t)(c0 + j) << 16) + (size_t)n]);
  return r;
}

// ======================= W prep ============================================
// Wt3: [2][192][64]  WqT,WkT (row = global dim, col = c)
// Wvb: [h][dc][ks][lane][8] B-frag-ready Wv
// WoT2:[64 co][192 dg]  = Wo[dg][co]
// fwb/qwb: [o][c] bf16 native
__global__ __launch_bounds__(256) void prep_w(
    const float* __restrict__ Wq, const float* __restrict__ Wk,
    const float* __restrict__ Wv, const float* __restrict__ Wo,
    const float* __restrict__ fw, const float* __restrict__ qw,
    short* __restrict__ Wt3, short* __restrict__ Wvb,
    short* __restrict__ WoT2, short* __restrict__ fwb, short* __restrict__ qwb)
{
  int i = blockIdx.x * 256 + threadIdx.x;
  if (i < 24576) {
    int m = i / 12288, rem = i % 12288;
    int r = rem >> 6, c = rem & 63;
    const float* W = m ? Wk : Wq;
    Wt3[i] = f2bf(W[c * 192 + r]);
  }
  if (i < 12288) {
    int h = i / 3072, rem = i % 3072;
    int j = rem & 7, ln = (rem >> 3) & 63, dcks = rem >> 9;
    int dc = dcks >> 1, ks = dcks & 1;
    int c = 32 * ks + 8 * (ln >> 4) + j;
    int col = 48 * h + 16 * dc + (ln & 15);
    Wvb[i] = f2bf(Wv[c * 192 + col]);
  }
  if (i < 12288) {
    int co = i / 192, dg = i % 192;
    WoT2[i] = f2bf(Wo[dg * 64 + co]);
  }
  if (i < 4096) { fwb[i] = f2bf(fw[i]); qwb[i] = f2bf(qw[i]); }
}

// ================= fused attention + freq + combine ========================
__global__ __launch_bounds__(256, 2) void attn_fused(
    const float* __restrict__ x, const short* __restrict__ Wt3,
    const short* __restrict__ Wvb, const short* __restrict__ WoT2,
    const short* __restrict__ qwb, const float* __restrict__ qbias,
    const short* __restrict__ ctxb16, const float* __restrict__ dw,
    float* __restrict__ out)
{
  __shared__ __align__(16) char xb_[8192];     // [64 t][64 c] bf16 swizzled
  __shared__ __align__(16) char ob_[25600];    // [64 t][200 dg] bf16 (192 used)

  const int tid = threadIdx.x, lane = tid & 63, w = tid >> 6;
  const int l15 = lane & 15, l4 = lane >> 4;
  const int srcA = l15 + 32 * (l4 & 1), srcB = srcA + 16;
  const bool hi = (l4 & 2) != 0;

  const int pid = blockIdx.x, b = pid >> 10, prem = pid & 1023;
  const int y0 = (prem >> 5) << 3, x0 = (prem & 31) << 3;
  const float* xg = x + ((size_t)b << 22);

  // ---- stage x -> xb[t][c] ----
#pragma unroll
  for (int k = 0; k < 16; ++k) {
    int idx = tid + (k << 8);
    int c = idx >> 6, t = idx & 63;
    float v = xg[((size_t)c << 16) + (size_t)((y0 + (t >> 3)) * 256 + x0 + (t & 7))];
    *(short*)(xb_ + LSWZ(t, c * 2)) = f2bf(v);
  }
  __syncthreads();

  const int h = w;   // wave = head

  // ---- qT, kT:  ZT[d][t] = sum_c WT[d][c] x[t][c]  (C: col=t, row=d) ----
  unsigned qpk[3][4][2], kpk[3][4][2];
#pragma unroll
  for (int m = 0; m < 2; ++m) {
    const short* WT = Wt3 + m * 12288 + (48 * h) * 64;
    bf16x8 a[3][2];
#pragma unroll
    for (int rp = 0; rp < 3; ++rp)
#pragma unroll
      for (int ks = 0; ks < 2; ++ks)
        a[rp][ks] = *(const bf16x8*)(WT + (16 * rp + l15) * 64 + 32 * ks + 8 * l4);
#pragma unroll
    for (int cq = 0; cq < 4; ++cq) {
      bf16x8 b0 = *(const bf16x8*)(xb_ + LSWZ(16 * cq + l15, 16 * l4));
      bf16x8 b1 = *(const bf16x8*)(xb_ + LSWZ(16 * cq + l15, 64 + 16 * l4));
#pragma unroll
      for (int rp = 0; rp < 3; ++rp) {
        f32x4 acc = (f32x4)0.f;
        acc = MFMA(a[rp][0], b0, acc);
        acc = MFMA(a[rp][1], b1, acc);
        unsigned* dst = m ? kpk[rp][cq] : qpk[rp][cq];
        dst[0] = pack2bf(acc[0], acc[1]);
        dst[1] = pack2bf(acc[2], acc[3]);
      }
    }
  }

  // ---- S^T = k @ qT (K=48, ks1 half-zero); softmax over u; pack P^T ----
  unsigned ppk[4][4][2];
  {
    bf16x8 Bq[4][2];
#pragma unroll
    for (int tt = 0; tt < 4; ++tt) {
      Bq[tt][0] = repack(qpk[0][tt][0], qpk[0][tt][1], qpk[1][tt][0], qpk[1][tt][1], srcA, srcB, hi);
      Bq[tt][1] = repack1(qpk[2][tt][0], qpk[2][tt][1], srcA, srcB, hi);
    }
    f32x4 st[4][4];
#pragma unroll
    for (int ur = 0; ur < 4; ++ur) {
      bf16x8 A0 = repack(kpk[0][ur][0], kpk[0][ur][1], kpk[1][ur][0], kpk[1][ur][1], srcA, srcB, hi);
      bf16x8 A1 = repack1(kpk[2][ur][0], kpk[2][ur][1], srcA, srcB, hi);
#pragma unroll
      for (int tt = 0; tt < 4; ++tt) {
        f32x4 acc = (f32x4)0.f;
        acc = MFMA(A0, Bq[tt][0], acc);
        acc = MFMA(A1, Bq[tt][1], acc);
        st[ur][tt] = acc;
      }
    }
#pragma unroll
    for (int tt = 0; tt < 4; ++tt) {
      float m = st[0][tt][0];
#pragma unroll
      for (int ur = 0; ur < 4; ++ur)
#pragma unroll
        for (int r = 0; r < 4; ++r) m = fmaxf(m, st[ur][tt][r]);
      m = fmaxf(m, __shfl_xor(m, 16, 64));
      m = fmaxf(m, __shfl_xor(m, 32, 64));
      float s = 0.f;
#pragma unroll
      for (int ur = 0; ur < 4; ++ur)
#pragma unroll
        for (int r = 0; r < 4; ++r) {
          float e = __expf(st[ur][tt][r] - m);
          st[ur][tt][r] = e; s += e;
        }
      s += __shfl_xor(s, 16, 64);
      s += __shfl_xor(s, 32, 64);
      const float inv = 1.f / s;
#pragma unroll
      for (int ur = 0; ur < 4; ++ur) {
        ppk[ur][tt][0] = pack2bf(st[ur][tt][0] * inv, st[ur][tt][1] * inv);
        ppk[ur][tt][1] = pack2bf(st[ur][tt][2] * inv, st[ur][tt][3] * inv);
      }
    }
  }

  // ---- v[u][d] = sum_c x[u][c] Wv[c][d]  (C: col=d, row=u) ----
  unsigned vpk[4][3][2];
  {
    const short* Wvh = Wvb + h * 3072;
    bf16x8 bv[3][2];
#pragma unroll
    for (int dc = 0; dc < 3; ++dc)
#pragma unroll
      for (int ks = 0; ks < 2; ++ks)
        bv[dc][ks] = *(const bf16x8*)(Wvh + ((dc * 2 + ks) * 64 + lane) * 8);
#pragma unroll
    for (int ur = 0; ur < 4; ++ur) {
      bf16x8 a0 = *(const bf16x8*)(xb_ + LSWZ(16 * ur + l15, 16 * l4));
      bf16x8 a1 = *(const bf16x8*)(xb_ + LSWZ(16 * ur + l15, 64 + 16 * l4));
#pragma unroll
      for (int dc = 0; dc < 3; ++dc) {
        f32x4 acc = (f32x4)0.f;
        acc = MFMA(a0, bv[dc][0], acc);
        acc = MFMA(a1, bv[dc][1], acc);
        vpk[ur][dc][0] = pack2bf(acc[0], acc[1]);
        vpk[ur][dc][1] = pack2bf(acc[2], acc[3]);
      }
    }
  }

  // ---- oT = vT @ P^T  -> ob[t][48h+dloc] ----
  {
    bf16x8 Bp[4][2];
#pragma unroll
    for (int tt = 0; tt < 4; ++tt) {
      Bp[tt][0] = repack(ppk[0][tt][0], ppk[0][tt][1], ppk[1][tt][0], ppk[1][tt][1], srcA, srcB, hi);
      Bp[tt][1] = repack(ppk[2][tt][0], ppk[2][tt][1], ppk[3][tt][0], ppk[3][tt][1], srcA, srcB, hi);
    }
#pragma unroll
    for (int dr = 0; dr < 3; ++dr) {
      bf16x8 A0 = repack(vpk[0][dr][0], vpk[0][dr][1], vpk[1][dr][0], vpk[1][dr][1], srcA, srcB, hi);
      bf16x8 A1 = repack(vpk[2][dr][0], vpk[2][dr][1], vpk[3][dr][0], vpk[3][dr][1], srcA, srcB, hi);
#pragma unroll
      for (int tt = 0; tt < 4; ++tt) {
        f32x4 acc = (f32x4)0.f;
        acc = MFMA(A0, Bp[tt][0], acc);
        acc = MFMA(A1, Bp[tt][1], acc);
        const int row = 16 * tt + l15;
        const int col = 48 * h + 16 * dr + 4 * l4;
        *(unsigned*)(ob_ + row * 400 + col * 2)     = pack2bf(acc[0], acc[1]);
        *(unsigned*)(ob_ + row * 400 + col * 2 + 4) = pack2bf(acc[2], acc[3]);
      }
    }
  }

  // ---- z (queries logits) for t-strip w: zT[o][t] = qw@x + qb; softmax(o) --
  unsigned pzpk[4][2];
  {
    bf16x8 xz0 = *(const bf16x8*)(xb_ + LSWZ(16 * w + l15, 16 * l4));
    bf16x8 xz1 = *(const bf16x8*)(xb_ + LSWZ(16 * w + l15, 64 + 16 * l4));
    f32x4 zt[4];
#pragma unroll
    for (int orr = 0; orr < 4; ++orr) {
      bf16x8 a0 = *(const bf16x8*)(qwb + (16 * orr + l15) * 64 + 8 * l4);
      bf16x8 a1 = *(const bf16x8*)(qwb + (16 * orr + l15) * 64 + 32 + 8 * l4);
      f32x4 acc;
#pragma unroll
      for (int r = 0; r < 4; ++r) acc[r] = qbias[16 * orr + 4 * l4 + r];
      acc = MFMA(a0, xz0, acc);
      acc = MFMA(a1, xz1, acc);
      zt[orr] = acc;
    }
    float m = zt[0][0];
#pragma unroll
    for (int orr = 0; orr < 4; ++orr)
#pragma unroll
      for (int r = 0; r < 4; ++r) m = fmaxf(m, zt[orr][r]);
    m = fmaxf(m, __shfl_xor(m, 16, 64));
    m = fmaxf(m, __shfl_xor(m, 32, 64));
    float s = 0.f;
#pragma unroll
    for (int orr = 0; orr < 4; ++orr)
#pragma unroll
      for (int r = 0; r < 4; ++r) { float e = __expf(zt[orr][r] - m); zt[orr][r] = e; s += e; }
    s += __shfl_xor(s, 16, 64);
    s += __shfl_xor(s, 32, 64);
    const float inv = 1.f / s;
#pragma unroll
    for (int orr = 0; orr < 4; ++orr) {
      pzpk[orr][0] = pack2bf(zt[orr][0] * inv, zt[orr][1] * inv);
      pzpk[orr][1] = pack2bf(zt[orr][2] * inv, zt[orr][3] * inv);
    }
  }
  __syncthreads();

  // ---- outT[co][t] = WoT2 @ o_all (K=192); freqT = ctx @ Pz; combine ----
  {
    f32x4 ot[4], ft[4];
#pragma unroll
    for (int kr = 0; kr < 4; ++kr) { ot[kr] = (f32x4)0.f; ft[kr] = (f32x4)0.f; }
#pragma unroll
    for (int ks = 0; ks < 6; ++ks) {
      bf16x8 bo = *(const bf16x8*)(ob_ + (16 * w + l15) * 400 + 64 * ks + 16 * l4);
#pragma unroll
      for (int kr = 0; kr < 4; ++kr) {
        bf16x8 a = *(const bf16x8*)(WoT2 + (16 * kr + l15) * 192 + 32 * ks + 8 * l4);
        ot[kr] = MFMA(a, bo, ot[kr]);
      }
    }
    {
      bf16x8 Bz0 = repack(pzpk[0][0], pzpk[0][1], pzpk[1][0], pzpk[1][1], srcA, srcB, hi);
      bf16x8 Bz1 = repack(pzpk[2][0], pzpk[2][1], pzpk[3][0], pzpk[3][1], srcA, srcB, hi);
      const short* cb = ctxb16 + ((size_t)b << 12);
#pragma unroll
      for (int kr = 0; kr < 4; ++kr) {
        bf16x8 a0 = *(const bf16x8*)(cb + (16 * kr + l15) * 64 + 8 * l4);
        bf16x8 a1 = *(const bf16x8*)(cb + (16 * kr + l15) * 64 + 32 + 8 * l4);
        ft[kr] = MFMA(a0, Bz0, ft[kr]);
        ft[kr] = MFMA(a1, Bz1, ft[kr]);
      }
    }
    const int t = 16 * w + l15;
    const size_t nbase = (size_t)((y0 + (t >> 3)) * 256 + x0 + (t & 7));
    float* og = out + ((size_t)b << 22);
#pragma unroll
    for (int kr = 0; kr < 4; ++kr)
#pragma unroll
      for (int r = 0; r < 4; ++r) {
        const int co = 16 * kr + 4 * l4 + r;
        og[((size_t)co << 16) + nbase] = ot[kr][r] * dw[2 * co] + ft[kr][r] * dw[2 * co + 1];
      }
  }
}

// =================== FMAM K1: Y = fw@x + fb (MFMA) =========================
__global__ __launch_bounds__(256) void fmam_y(
    const float* __restrict__ x, const short* __restrict__ fwb,
    const float* __restrict__ fb, short* __restrict__ Y,
    float* __restrict__ kpart)
{
  __shared__ float red[4 * 64 * 2];
  const int tid = threadIdx.x, lane = tid & 63, w = tid >> 6;
  const int l15 = lane & 15, l4 = lane >> 4;
  const int chunk = blockIdx.x, b = blockIdx.y;
  const float* xg = x + ((size_t)b << 22);
  short* yg = Y + ((size_t)b << 22);
  const int n0 = (chunk << 8) + (w << 6);

  bf16x8 af[4][2];
#pragma unroll
  for (int ot = 0; ot < 4; ++ot)
#pragma unroll
    for (int ks = 0; ks < 2; ++ks)
      af[ot][ks] = *(const bf16x8*)(fwb + (ot * 16 + l15) * 64 + ks * 32 + l4 * 8);
  float4 fbv[4];
#pragma unroll
  for (int ot = 0; ot < 4; ++ot) fbv[ot] = *(const float4*)(fb + ot * 16 + l4 * 4);

  float m_l[16], s_l[16];
#pragma unroll
  for (int i = 0; i < 16; ++i) { m_l[i] = -1e30f; s_l[i] = 0.f; }

#pragma unroll
  for (int nt = 0; nt < 4; ++nt) {
    const int n = n0 + nt * 16 + l15;
    bf16x8 bf0 = load_xfrag(xg, l4 * 8, n);
    bf16x8 bf1 = load_xfrag(xg, 32 + l4 * 8, n);
#pragma unroll
    for (int ot = 0; ot < 4; ++ot) {
      f32x4 acc;
      acc[0] = fbv[ot].x; acc[1] = fbv[ot].y; acc[2] = fbv[ot].z; acc[3] = fbv[ot].w;
      acc = MFMA(af[ot][0], bf0, acc);
      acc = MFMA(af[ot][1], bf1, acc);
#pragma unroll
      for (int r = 0; r < 4; ++r) {
        short yb = f2bf(acc[r]);
        yg[((size_t)(ot * 16 + l4 * 4 + r) << 16) + (size_t)n] = yb;
        float yr = bf2f(yb);
        const int i = ot * 4 + r;
        float nm = fmaxf(m_l[i], yr);
        s_l[i] = s_l[i] * __expf(m_l[i] - nm) + __expf(yr - nm);
        m_l[i] = nm;
      }
    }
  }
#pragma unroll
  for (int i = 0; i < 16; ++i) {
#pragma unroll
    for (int msk = 1; msk <= 8; msk <<= 1) {
      float om = __shfl_xor(m_l[i], msk, 64);
      float os = __shfl_xor(s_l[i], msk, 64);
      float nm = fmaxf(m_l[i], om);
      s_l[i] = s_l[i] * __expf(m_l[i] - nm) + os * __expf(om - nm);
      m_l[i] = nm;
    }
  }
  if (l15 == 0) {
#pragma unroll
    for (int ot = 0; ot < 4; ++ot)
#pragma unroll
      for (int r = 0; r < 4; ++r) {
        const int o = ot * 16 + l4 * 4 + r;
        red[(w * 64 + o) * 2]     = m_l[ot * 4 + r];
        red[(w * 64 + o) * 2 + 1] = s_l[ot * 4 + r];
      }
  }
  __syncthreads();
  if (tid < 64) {
    float M = red[tid * 2], S = red[tid * 2 + 1];
#pragma unroll
    for (int g = 1; g < 4; ++g) {
      const float m2 = red[((g << 6) + tid) * 2], s2 = red[((g << 6) + tid) * 2 + 1];
      const float nm = fmaxf(M, m2);
      S = S * __expf(M - nm) + s2 * __expf(m2 - nm);
      M = nm;
    }
    kpart[(((b << 8) + chunk) * 64 + tid) * 2]     = M;
    kpart[(((b << 8) + chunk) * 64 + tid) * 2 + 1] = S;
  }
}

// =================== FMAM: combine per-chunk stats =========================
__global__ void fmam_kreduce(const float* __restrict__ kpart, float* __restrict__ kstats)
{
  const int bo = blockIdx.x;
  const int b = bo >> 6, o = bo & 63;
  const int lane = threadIdx.x;
  float M = -1e30f, S = 0.f;
  for (int ch = lane; ch < 256; ch += 64) {
    const float* pp = kpart + ((size_t)(((b << 8) + ch) * 64 + o)) * 2;
    const float m2 = pp[0], s2 = pp[1];
    const float nm = fmaxf(M, m2);
    S = S * __expf(M - nm) + s2 * __expf(m2 - nm);
    M = nm;
  }
  for (int msk = 1; msk < 64; msk <<= 1) {
    const float m2 = __shfl_xor(M, msk, 64);
    const float s2 = __shfl_xor(S, msk, 64);
    const float nm = fmaxf(M, m2);
    S = S * __expf(M - nm) + s2 * __expf(m2 - nm);
    M = nm;
  }
  if (lane == 0) { kstats[bo * 2] = M; kstats[bo * 2 + 1] = 1.f / S; }
}

// =================== FMAM K3: ctx partials via MFMA ========================
__global__ __launch_bounds__(256) void fmam_ctx_mfma(
    const float* __restrict__ x, const short* __restrict__ Y,
    const float* __restrict__ kstats, float* __restrict__ ctxpart)
{
  const int tid = threadIdx.x, lane = tid & 63, w = tid >> 6;
  const int l15 = lane & 15, l4 = lane >> 4;
  const int chunk = blockIdx.x, b = blockIdx.y;
  const float* xg = x + ((size_t)b << 22);
  const short* yg = Y + ((size_t)b << 22);
  const int n0 = chunk << 8;

  float M[4], IS[4];
#pragma unroll
  for (int ot = 0; ot < 4; ++ot) {
    const int o = ot * 16 + l15;
    M[ot]  = kstats[((b << 6) + o) * 2];
    IS[ot] = kstats[((b << 6) + o) * 2 + 1];
  }
  f32x4 acc[4];
#pragma unroll
  for (int i = 0; i < 4; ++i) acc[i] = (f32x4)0.f;

#pragma unroll
  for (int ks = 0; ks < 8; ++ks) {
    const int nk = n0 + ks * 32 + l4 * 8;
    const float* xr = xg + ((size_t)(w * 16 + l15) << 16) + nk;
    const float4 xa = *(const float4*)xr;
    const float4 xb2 = *(const float4*)(xr + 4);
    bf16x8 bfr;
    bfr[0] = f2bf(xa.x); bfr[1] = f2bf(xa.y); bfr[2] = f2bf(xa.z); bfr[3] = f2bf(xa.w);
    bfr[4] = f2bf(xb2.x); bfr[5] = f2bf(xb2.y); bfr[6] = f2bf(xb2.z); bfr[7] = f2bf(xb2.w);
#pragma unroll
    for (int ot = 0; ot < 4; ++ot) {
      bf16x8 ya = *(const bf16x8*)(yg + ((size_t)(ot * 16 + l15) << 16) + nk);
      bf16x8 pa;
#pragma unroll
      for (int j = 0; j < 8; ++j)
        pa[j] = f2bf(__expf(bf2f(ya[j]) - M[ot]) * IS[ot]);
      acc[ot] = MFMA(pa, bfr, acc[ot]);
    }
  }
  float* cp = ctxpart + ((((size_t)b << 8) + chunk) << 12);
#pragma unroll
  for (int ot = 0; ot < 4; ++ot)
#pragma unroll
    for (int r = 0; r < 4; ++r)
      cp[(ot * 16 + l4 * 4 + r) * 64 + w * 16 + l15] = acc[ot][r];
}

// =================== FMAM: reduce ctx partials -> bf16 ctx =================
__global__ __launch_bounds__(256) void fmam_ctxreduce(
    const float* __restrict__ ctxpart, short* __restrict__ ctxb16)
{
  __shared__ float red[256];
  const int bo = blockIdx.x;
  const int b = bo >> 6, o = bo & 63;
  const int tid = threadIdx.x;
  const int c = tid & 63, cg = tid >> 6;
  const float* p = ctxpart + ((size_t)b << 20) + (o << 6) + c;
  float s = 0.f;
  for (int ch = cg * 64; ch < cg * 64 + 64; ++ch) s += p[(size_t)ch << 12];
  red[tid] = s;
  __syncthreads();
  if (tid < 64) {
    const float v = red[tid] + red[tid + 64] + red[tid + 128] + red[tid + 192];
    ctxb16[(bo << 6) + tid] = f2bf(v);   // ctx_g[b][k][c]
  }
}

// ===========================================================================
extern "C" void kernel_launch(void* const* d_in, const int* in_sizes, int n_in,
                              void* d_out, int out_size, void* d_ws, size_t ws_size,
                              hipStream_t stream) {
  const float* x  = (const float*)d_in[0];
  const float* Wq = (const float*)d_in[1];
  const float* Wk = (const float*)d_in[2];
  const float* Wv = (const float*)d_in[3];
  const float* Wo = (const float*)d_in[4];
  const float* qw = (const float*)d_in[7];
  const float* qb = (const float*)d_in[8];
  const float* fw = (const float*)d_in[9];
  const float* fb = (const float*)d_in[10];
  const float* dw = (const float*)d_in[11];
  float* out = (float*)d_out;

  float* ws = (float*)d_ws;
  short* Y       = (short*)ws;               // [2][64][65536] bf16 = 16MB
  float* kpart   = ws + 8388608;             // byte 32MB
  float* kstats  = kpart + 65536;
  float* ctxpart = kstats + 256;             // 8MB
  short* wbuf    = (short*)(ctxpart + 2097152);
  short* Wt3  = wbuf;                        // 24576
  short* Wvb  = Wt3 + 24576;                 // 12288
  short* WoT2 = Wvb + 12288;                 // 12288
  short* fwb  = WoT2 + 12288;                // 4096
  short* qwb  = fwb + 4096;                  // 4096
  short* ctxb16 = qwb + 4096;                // 8192

  hipLaunchKernelGGL(prep_w, dim3(96), dim3(256), 0, stream,
                     Wq, Wk, Wv, Wo, fw, qw, Wt3, Wvb, WoT2, fwb, qwb);
  hipLaunchKernelGGL(fmam_y, dim3(256, 2), dim3(256), 0, stream, x, fwb, fb, Y, kpart);
  hipLaunchKernelGGL(fmam_kreduce, dim3(128), dim3(64), 0, stream, kpart, kstats);
  hipLaunchKernelGGL(fmam_ctx_mfma, dim3(256, 2), dim3(256), 0, stream, x, Y, kstats, ctxpart);
  hipLaunchKernelGGL(fmam_ctxreduce, dim3(128), dim3(256), 0, stream, ctxpart, ctxb16);
  hipLaunchKernelGGL(attn_fused, dim3(2048), dim3(256), 0, stream,
                     x, Wt3, Wvb, WoT2, qwb, qb, ctxb16, dw, out);
}

// Round 6
// 125.040 us; speedup vs baseline: 6.0758x; 1.0879x over previous
//
#include <hip/hip_runtime.h>
#include <hip/hip_bf16.h>

// ---------------------------------------------------------------------------
// FPSAttn. LSH machinery is a no-op (full attention over the permuted patch,
// inverse-permuted; rounds identical, probs==0.5).
//   out = spa*dw0 + freq*dw1
//   spa  = patch 4-head attention + Wo   (fused kernel, wave-per-head)
//   freq = FMAM; ctx via SINGLE-PASS no-max softmax (|logit| <= ~1, exp safe),
//          queries-softmax fused into the attention epilogue.
// MFMA frag conventions (HW-verified rounds 1-5):
//   A-frag: lane(l15,l4) holds A[16*rt + l15][32*ks + 8*l4 + j], j=0..7
//   B-frag: lane holds B[32*ks + 8*l4 + j][16*ct + l15]
//   C-frag: lane holds C[16*rt + 4*l4 + r][16*ct + l15], r=0..3
// Repack identity (HW-verified r4/r5): C-frag of Z (row R, col Q) -> A/B-frag
// of Z as [k=R][l15=Q] via same-l15 lane permutation (srcA/srcB/hi below).
// ---------------------------------------------------------------------------

typedef __attribute__((ext_vector_type(8))) short bf16x8;
typedef __attribute__((ext_vector_type(4))) float f32x4;
typedef __attribute__((ext_vector_type(4))) unsigned u32x4;

static __device__ __forceinline__ short f2bf(float f) {
  __hip_bfloat16 h = __float2bfloat16(f);
  return *reinterpret_cast<short*>(&h);
}
static __device__ __forceinline__ float bf2f(short s) {
  return __uint_as_float(((unsigned)(unsigned short)s) << 16);
}
// pack two f32 -> one u32 of 2 bf16 (low = a, high = b). Pure C++ (m240).
static __device__ __forceinline__ unsigned pack2bf(float a, float b) {
  return (unsigned)(unsigned short)f2bf(a) | ((unsigned)(unsigned short)f2bf(b) << 16);
}
static __device__ __forceinline__ f32x4 MFMA(bf16x8 a, bf16x8 b, f32x4 c) {
  return __builtin_amdgcn_mfma_f32_16x16x32_bf16(a, b, c, 0, 0, 0);
}

// swizzled byte offset into a [rows][64] bf16 LDS tile (128B rows)
#define LSWZ(row, bytecol) ((((row) << 7) + (bytecol)) ^ (((row) & 7) << 4))

// Repack two packed C-frag tiles (L = slab rows [0,16), H = rows [16,32))
// into an MFMA A/B-frag. pl0/pl1 = pack2bf(acc0,acc1)/(acc2,acc3).
static __device__ __forceinline__ bf16x8 repack(
    unsigned pl0, unsigned pl1, unsigned ph0, unsigned ph1,
    int srcA, int srcB, bool hi) {
  unsigned l0 = __shfl((int)pl0, srcA, 64), l1 = __shfl((int)pl1, srcA, 64);
  unsigned l2 = __shfl((int)pl0, srcB, 64), l3 = __shfl((int)pl1, srcB, 64);
  unsigned h0 = __shfl((int)ph0, srcA, 64), h1 = __shfl((int)ph1, srcA, 64);
  unsigned h2 = __shfl((int)ph0, srcB, 64), h3 = __shfl((int)ph1, srcB, 64);
  u32x4 v;
  v[0] = hi ? h0 : l0; v[1] = hi ? h1 : l1;
  v[2] = hi ? h2 : l2; v[3] = hi ? h3 : l3;
  return __builtin_bit_cast(bf16x8, v);
}
// variant: H tile is all-zero (K-padding)
static __device__ __forceinline__ bf16x8 repack1(
    unsigned pl0, unsigned pl1, int srcA, int srcB, bool hi) {
  unsigned l0 = __shfl((int)pl0, srcA, 64), l1 = __shfl((int)pl1, srcA, 64);
  unsigned l2 = __shfl((int)pl0, srcB, 64), l3 = __shfl((int)pl1, srcB, 64);
  u32x4 v;
  v[0] = hi ? 0u : l0; v[1] = hi ? 0u : l1;
  v[2] = hi ? 0u : l2; v[3] = hi ? 0u : l3;
  return __builtin_bit_cast(bf16x8, v);
}

// frag of x from global [c][n]: lane supplies x[c0+j][n]
static __device__ __forceinline__ bf16x8 load_xfrag(const float* xg, int c0, int n) {
  bf16x8 r;
#pragma unroll
  for (int j = 0; j < 8; ++j) r[j] = f2bf(xg[((size_t)(c0 + j) << 16) + (size_t)n]);
  return r;
}

// ======================= W prep ============================================
// Wt3: [2][192][64]  WqT,WkT (row = global dim, col = c)
// Wvb: [h][dc][ks][lane][8] B-frag-ready Wv
// WoT2:[64 co][192 dg]  = Wo[dg][co]
// fwb/qwb: [o][c] bf16 native
__global__ __launch_bounds__(256) void prep_w(
    const float* __restrict__ Wq, const float* __restrict__ Wk,
    const float* __restrict__ Wv, const float* __restrict__ Wo,
    const float* __restrict__ fw, const float* __restrict__ qw,
    short* __restrict__ Wt3, short* __restrict__ Wvb,
    short* __restrict__ WoT2, short* __restrict__ fwb, short* __restrict__ qwb)
{
  int i = blockIdx.x * 256 + threadIdx.x;
  if (i < 24576) {
    int m = i / 12288, rem = i % 12288;
    int r = rem >> 6, c = rem & 63;
    const float* W = m ? Wk : Wq;
    Wt3[i] = f2bf(W[c * 192 + r]);
  }
  if (i < 12288) {
    int h = i / 3072, rem = i % 3072;
    int j = rem & 7, ln = (rem >> 3) & 63, dcks = rem >> 9;
    int dc = dcks >> 1, ks = dcks & 1;
    int c = 32 * ks + 8 * (ln >> 4) + j;
    int col = 48 * h + 16 * dc + (ln & 15);
    Wvb[i] = f2bf(Wv[c * 192 + col]);
  }
  if (i < 12288) {
    int co = i / 192, dg = i % 192;
    WoT2[i] = f2bf(Wo[dg * 64 + co]);
  }
  if (i < 4096) { fwb[i] = f2bf(fw[i]); qwb[i] = f2bf(qw[i]); }
}

// ================= fused attention + freq + combine ========================
__global__ __launch_bounds__(256, 4) void attn_fused(
    const float* __restrict__ x, const short* __restrict__ Wt3,
    const short* __restrict__ Wvb, const short* __restrict__ WoT2,
    const short* __restrict__ qwb, const float* __restrict__ qbias,
    const short* __restrict__ ctxb16, const float* __restrict__ dw,
    float* __restrict__ out)
{
  __shared__ __align__(16) char xb_[8192];     // [64 t][64 c] bf16 swizzled
  __shared__ __align__(16) char ob_[25600];    // [64 t][200 dg] bf16 (192 used)

  const int tid = threadIdx.x, lane = tid & 63, w = tid >> 6;
  const int l15 = lane & 15, l4 = lane >> 4;
  const int srcA = l15 + 32 * (l4 & 1), srcB = srcA + 16;
  const bool hi = (l4 & 2) != 0;

  const int pid = blockIdx.x, b = pid >> 10, prem = pid & 1023;
  const int y0 = (prem >> 5) << 3, x0 = (prem & 31) << 3;
  const float* xg = x + ((size_t)b << 22);

  // ---- stage x -> xb[t][c] ----
#pragma unroll
  for (int k = 0; k < 16; ++k) {
    int idx = tid + (k << 8);
    int c = idx >> 6, t = idx & 63;
    float v = xg[((size_t)c << 16) + (size_t)((y0 + (t >> 3)) * 256 + x0 + (t & 7))];
    *(short*)(xb_ + LSWZ(t, c * 2)) = f2bf(v);
  }
  __syncthreads();

  const int h = w;   // wave = head

  // ---- qT, kT:  ZT[d][t] = sum_c WT[d][c] x[t][c]  (C: col=t, row=d) ----
  unsigned qpk[3][4][2], kpk[3][4][2];
#pragma unroll
  for (int m = 0; m < 2; ++m) {
    const short* WT = Wt3 + m * 12288 + (48 * h) * 64;
    bf16x8 a[3][2];
#pragma unroll
    for (int rp = 0; rp < 3; ++rp)
#pragma unroll
      for (int ks = 0; ks < 2; ++ks)
        a[rp][ks] = *(const bf16x8*)(WT + (16 * rp + l15) * 64 + 32 * ks + 8 * l4);
#pragma unroll
    for (int cq = 0; cq < 4; ++cq) {
      bf16x8 b0 = *(const bf16x8*)(xb_ + LSWZ(16 * cq + l15, 16 * l4));
      bf16x8 b1 = *(const bf16x8*)(xb_ + LSWZ(16 * cq + l15, 64 + 16 * l4));
#pragma unroll
      for (int rp = 0; rp < 3; ++rp) {
        f32x4 acc = (f32x4)0.f;
        acc = MFMA(a[rp][0], b0, acc);
        acc = MFMA(a[rp][1], b1, acc);
        unsigned* dst = m ? kpk[rp][cq] : qpk[rp][cq];
        dst[0] = pack2bf(acc[0], acc[1]);
        dst[1] = pack2bf(acc[2], acc[3]);
      }
    }
  }

  // ---- S^T = k @ qT (K=48, ks1 half-zero); softmax over u; pack P^T ----
  unsigned ppk[4][4][2];
  {
    bf16x8 Bq[4][2];
#pragma unroll
    for (int tt = 0; tt < 4; ++tt) {
      Bq[tt][0] = repack(qpk[0][tt][0], qpk[0][tt][1], qpk[1][tt][0], qpk[1][tt][1], srcA, srcB, hi);
      Bq[tt][1] = repack1(qpk[2][tt][0], qpk[2][tt][1], srcA, srcB, hi);
    }
    f32x4 st[4][4];
#pragma unroll
    for (int ur = 0; ur < 4; ++ur) {
      bf16x8 A0 = repack(kpk[0][ur][0], kpk[0][ur][1], kpk[1][ur][0], kpk[1][ur][1], srcA, srcB, hi);
      bf16x8 A1 = repack1(kpk[2][ur][0], kpk[2][ur][1], srcA, srcB, hi);
#pragma unroll
      for (int tt = 0; tt < 4; ++tt) {
        f32x4 acc = (f32x4)0.f;
        acc = MFMA(A0, Bq[tt][0], acc);
        acc = MFMA(A1, Bq[tt][1], acc);
        st[ur][tt] = acc;
      }
    }
#pragma unroll
    for (int tt = 0; tt < 4; ++tt) {
      float m = st[0][tt][0];
#pragma unroll
      for (int ur = 0; ur < 4; ++ur)
#pragma unroll
        for (int r = 0; r < 4; ++r) m = fmaxf(m, st[ur][tt][r]);
      m = fmaxf(m, __shfl_xor(m, 16, 64));
      m = fmaxf(m, __shfl_xor(m, 32, 64));
      float s = 0.f;
#pragma unroll
      for (int ur = 0; ur < 4; ++ur)
#pragma unroll
        for (int r = 0; r < 4; ++r) {
          float e = __expf(st[ur][tt][r] - m);
          st[ur][tt][r] = e; s += e;
        }
      s += __shfl_xor(s, 16, 64);
      s += __shfl_xor(s, 32, 64);
      const float inv = 1.f / s;
#pragma unroll
      for (int ur = 0; ur < 4; ++ur) {
        ppk[ur][tt][0] = pack2bf(st[ur][tt][0] * inv, st[ur][tt][1] * inv);
        ppk[ur][tt][1] = pack2bf(st[ur][tt][2] * inv, st[ur][tt][3] * inv);
      }
    }
  }

  // ---- v[u][d] = sum_c x[u][c] Wv[c][d]  (C: col=d, row=u) ----
  unsigned vpk[4][3][2];
  {
    const short* Wvh = Wvb + h * 3072;
    bf16x8 bv[3][2];
#pragma unroll
    for (int dc = 0; dc < 3; ++dc)
#pragma unroll
      for (int ks = 0; ks < 2; ++ks)
        bv[dc][ks] = *(const bf16x8*)(Wvh + ((dc * 2 + ks) * 64 + lane) * 8);
#pragma unroll
    for (int ur = 0; ur < 4; ++ur) {
      bf16x8 a0 = *(const bf16x8*)(xb_ + LSWZ(16 * ur + l15, 16 * l4));
      bf16x8 a1 = *(const bf16x8*)(xb_ + LSWZ(16 * ur + l15, 64 + 16 * l4));
#pragma unroll
      for (int dc = 0; dc < 3; ++dc) {
        f32x4 acc = (f32x4)0.f;
        acc = MFMA(a0, bv[dc][0], acc);
        acc = MFMA(a1, bv[dc][1], acc);
        vpk[ur][dc][0] = pack2bf(acc[0], acc[1]);
        vpk[ur][dc][1] = pack2bf(acc[2], acc[3]);
      }
    }
  }

  // ---- oT = vT @ P^T  -> ob[t][48h+dloc] ----
  {
    bf16x8 Bp[4][2];
#pragma unroll
    for (int tt = 0; tt < 4; ++tt) {
      Bp[tt][0] = repack(ppk[0][tt][0], ppk[0][tt][1], ppk[1][tt][0], ppk[1][tt][1], srcA, srcB, hi);
      Bp[tt][1] = repack(ppk[2][tt][0], ppk[2][tt][1], ppk[3][tt][0], ppk[3][tt][1], srcA, srcB, hi);
    }
#pragma unroll
    for (int dr = 0; dr < 3; ++dr) {
      bf16x8 A0 = repack(vpk[0][dr][0], vpk[0][dr][1], vpk[1][dr][0], vpk[1][dr][1], srcA, srcB, hi);
      bf16x8 A1 = repack(vpk[2][dr][0], vpk[2][dr][1], vpk[3][dr][0], vpk[3][dr][1], srcA, srcB, hi);
#pragma unroll
      for (int tt = 0; tt < 4; ++tt) {
        f32x4 acc = (f32x4)0.f;
        acc = MFMA(A0, Bp[tt][0], acc);
        acc = MFMA(A1, Bp[tt][1], acc);
        const int row = 16 * tt + l15;
        const int col = 48 * h + 16 * dr + 4 * l4;
        *(unsigned*)(ob_ + row * 400 + col * 2)     = pack2bf(acc[0], acc[1]);
        *(unsigned*)(ob_ + row * 400 + col * 2 + 4) = pack2bf(acc[2], acc[3]);
      }
    }
  }

  // ---- z (queries logits) for t-strip w: zT[o][t] = qw@x + qb; softmax(o) --
  unsigned pzpk[4][2];
  {
    bf16x8 xz0 = *(const bf16x8*)(xb_ + LSWZ(16 * w + l15, 16 * l4));
    bf16x8 xz1 = *(const bf16x8*)(xb_ + LSWZ(16 * w + l15, 64 + 16 * l4));
    f32x4 zt[4];
#pragma unroll
    for (int orr = 0; orr < 4; ++orr) {
      bf16x8 a0 = *(const bf16x8*)(qwb + (16 * orr + l15) * 64 + 8 * l4);
      bf16x8 a1 = *(const bf16x8*)(qwb + (16 * orr + l15) * 64 + 32 + 8 * l4);
      f32x4 acc;
#pragma unroll
      for (int r = 0; r < 4; ++r) acc[r] = qbias[16 * orr + 4 * l4 + r];
      acc = MFMA(a0, xz0, acc);
      acc = MFMA(a1, xz1, acc);
      zt[orr] = acc;
    }
    float m = zt[0][0];
#pragma unroll
    for (int orr = 0; orr < 4; ++orr)
#pragma unroll
      for (int r = 0; r < 4; ++r) m = fmaxf(m, zt[orr][r]);
    m = fmaxf(m, __shfl_xor(m, 16, 64));
    m = fmaxf(m, __shfl_xor(m, 32, 64));
    float s = 0.f;
#pragma unroll
    for (int orr = 0; orr < 4; ++orr)
#pragma unroll
      for (int r = 0; r < 4; ++r) { float e = __expf(zt[orr][r] - m); zt[orr][r] = e; s += e; }
    s += __shfl_xor(s, 16, 64);
    s += __shfl_xor(s, 32, 64);
    const float inv = 1.f / s;
#pragma unroll
    for (int orr = 0; orr < 4; ++orr) {
      pzpk[orr][0] = pack2bf(zt[orr][0] * inv, zt[orr][1] * inv);
      pzpk[orr][1] = pack2bf(zt[orr][2] * inv, zt[orr][3] * inv);
    }
  }
  __syncthreads();

  // ---- outT[co][t] = WoT2 @ o_all (K=192); freqT = ctx @ Pz; combine ----
  {
    f32x4 ot[4], ft[4];
#pragma unroll
    for (int kr = 0; kr < 4; ++kr) { ot[kr] = (f32x4)0.f; ft[kr] = (f32x4)0.f; }
#pragma unroll
    for (int ks = 0; ks < 6; ++ks) {
      bf16x8 bo = *(const bf16x8*)(ob_ + (16 * w + l15) * 400 + 64 * ks + 16 * l4);
#pragma unroll
      for (int kr = 0; kr < 4; ++kr) {
        bf16x8 a = *(const bf16x8*)(WoT2 + (16 * kr + l15) * 192 + 32 * ks + 8 * l4);
        ot[kr] = MFMA(a, bo, ot[kr]);
      }
    }
    {
      bf16x8 Bz0 = repack(pzpk[0][0], pzpk[0][1], pzpk[1][0], pzpk[1][1], srcA, srcB, hi);
      bf16x8 Bz1 = repack(pzpk[2][0], pzpk[2][1], pzpk[3][0], pzpk[3][1], srcA, srcB, hi);
      const short* cb = ctxb16 + ((size_t)b << 12);
#pragma unroll
      for (int kr = 0; kr < 4; ++kr) {
        bf16x8 a0 = *(const bf16x8*)(cb + (16 * kr + l15) * 64 + 8 * l4);
        bf16x8 a1 = *(const bf16x8*)(cb + (16 * kr + l15) * 64 + 32 + 8 * l4);
        ft[kr] = MFMA(a0, Bz0, ft[kr]);
        ft[kr] = MFMA(a1, Bz1, ft[kr]);
      }
    }
    const int t = 16 * w + l15;
    const size_t nbase = (size_t)((y0 + (t >> 3)) * 256 + x0 + (t & 7));
    float* og = out + ((size_t)b << 22);
#pragma unroll
    for (int kr = 0; kr < 4; ++kr)
#pragma unroll
      for (int r = 0; r < 4; ++r) {
        const int co = 16 * kr + 4 * l4 + r;
        og[((size_t)co << 16) + nbase] = ot[kr][r] * dw[2 * co] + ft[kr][r] * dw[2 * co + 1];
      }
  }
}

// ========== FMAM single-pass: ctx partials + esum (no-max softmax) =========
// Per (b, chunk of 256 n), wave strip = 64 n. For each 32-n slab:
//   Y^T[n][o] = x^T @ fw^T + fb  (MFMA, C: row=n, col=o)
//   E = exp(Y) in-register (|Y| <~ 1, overflow-free), repack -> B-frag [n][o]
//   ctx[c][o] += x-frag[c][n] @ E[n][o]   (MFMA)
// Wave partials reduced across waves in LDS; per-chunk [o][c] + esum[o] out.
__global__ __launch_bounds__(256) void fmam_ctx1(
    const float* __restrict__ x, const short* __restrict__ fwb,
    const float* __restrict__ fb, float* __restrict__ ctxpart,
    float* __restrict__ epart)
{
  __shared__ float cred[4][64 * 68];   // [wave][o*68 + c] (pad 68: 2-way banks)
  __shared__ float ered[4][64];
  const int tid = threadIdx.x, lane = tid & 63, w = tid >> 6;
  const int l15 = lane & 15, l4 = lane >> 4;
  const int srcA = l15 + 32 * (l4 & 1), srcB = srcA + 16;
  const bool hi = (l4 & 2) != 0;
  const int chunk = blockIdx.x, b = blockIdx.y;
  const float* xg = x + ((size_t)b << 22);
  const int n0 = (chunk << 8) + (w << 6);

  // B-frags of fw^T: B[c][o] = fw[o][c] -> contiguous in fwb[o*64+c]
  bf16x8 Bfw[4][2];
#pragma unroll
  for (int ct = 0; ct < 4; ++ct)
#pragma unroll
    for (int ks = 0; ks < 2; ++ks)
      Bfw[ct][ks] = *(const bf16x8*)(fwb + (16 * ct + l15) * 64 + 32 * ks + 8 * l4);
  float fbl[4];
#pragma unroll
  for (int ct = 0; ct < 4; ++ct) fbl[ct] = fb[16 * ct + l15];

  f32x4 acc[4][4];   // [rt2 c-tile][ct o-tile]
#pragma unroll
  for (int i = 0; i < 4; ++i)
#pragma unroll
    for (int j = 0; j < 4; ++j) acc[i][j] = (f32x4)0.f;
  float esum[4] = {0.f, 0.f, 0.f, 0.f};

#pragma unroll
  for (int ns = 0; ns < 2; ++ns) {
    const int nb = n0 + 32 * ns;
    // A-frags x^T (row n, k c): lane j -> x[32ks+8l4+j][nb+16rt+l15]
    bf16x8 axT[2][2];
#pragma unroll
    for (int rt = 0; rt < 2; ++rt)
#pragma unroll
      for (int ks = 0; ks < 2; ++ks)
        axT[rt][ks] = load_xfrag(xg, 32 * ks + 8 * l4, nb + 16 * rt + l15);
    unsigned pl[4][2][2];   // [ct][rt(L/H)][pair]
#pragma unroll
    for (int rt = 0; rt < 2; ++rt)
#pragma unroll
      for (int ct = 0; ct < 4; ++ct) {
        f32x4 yt = (f32x4)(fbl[ct]);
        yt = MFMA(axT[rt][0], Bfw[ct][0], yt);
        yt = MFMA(axT[rt][1], Bfw[ct][1], yt);
        float e0 = __expf(yt[0]), e1 = __expf(yt[1]);
        float e2 = __expf(yt[2]), e3 = __expf(yt[3]);
        esum[ct] += (e0 + e1) + (e2 + e3);
        pl[ct][rt][0] = pack2bf(e0, e1);
        pl[ct][rt][1] = pack2bf(e2, e3);
      }
    // A-frags x (row c, k n): contiguous float4x2 per lane
    bf16x8 axc[4];
#pragma unroll
    for (int rt2 = 0; rt2 < 4; ++rt2) {
      const float* xr = xg + ((size_t)(16 * rt2 + l15) << 16) + nb + 8 * l4;
      const float4 a4 = *(const float4*)xr;
      const float4 b4 = *(const float4*)(xr + 4);
      bf16x8 f;
      f[0] = f2bf(a4.x); f[1] = f2bf(a4.y); f[2] = f2bf(a4.z); f[3] = f2bf(a4.w);
      f[4] = f2bf(b4.x); f[5] = f2bf(b4.y); f[6] = f2bf(b4.z); f[7] = f2bf(b4.w);
      axc[rt2] = f;
    }
#pragma unroll
    for (int ct = 0; ct < 4; ++ct) {
      bf16x8 Bp = repack(pl[ct][0][0], pl[ct][0][1], pl[ct][1][0], pl[ct][1][1],
                         srcA, srcB, hi);
#pragma unroll
      for (int rt2 = 0; rt2 < 4; ++rt2)
        acc[rt2][ct] = MFMA(axc[rt2], Bp, acc[rt2][ct]);
    }
  }
  // esum: reduce across l4 groups (rows); lane l15 of each group has o-total
#pragma unroll
  for (int ct = 0; ct < 4; ++ct) {
    esum[ct] += __shfl_xor(esum[ct], 16, 64);
    esum[ct] += __shfl_xor(esum[ct], 32, 64);
  }
  if (l4 == 0) {
#pragma unroll
    for (int ct = 0; ct < 4; ++ct) ered[w][16 * ct + l15] = esum[ct];
  }
  // ctx partials -> LDS (C-frag: row=c=16rt2+4l4+r, col=o=16ct+l15)
#pragma unroll
  for (int ct = 0; ct < 4; ++ct)
#pragma unroll
    for (int rt2 = 0; rt2 < 4; ++rt2)
      *(f32x4*)&cred[w][(16 * ct + l15) * 68 + 16 * rt2 + 4 * l4] = acc[rt2][ct];
  __syncthreads();
  // combine 4 waves, write per-chunk partials
  float* cp = ctxpart + ((((size_t)b << 8) + chunk) << 12);
  for (int i = tid; i < 4096; i += 256) {
    const int o = i >> 6, c = i & 63;
    const int li = o * 68 + c;
    cp[i] = (cred[0][li] + cred[1][li]) + (cred[2][li] + cred[3][li]);
  }
  if (tid < 64)
    epart[(((b << 8) + chunk) << 6) + tid] =
        (ered[0][tid] + ered[1][tid]) + (ered[2][tid] + ered[3][tid]);
}

// ====== reduce ctx partials over chunks, divide by esum, emit bf16 ========
__global__ __launch_bounds__(256) void fmam_ctxreduce2(
    const float* __restrict__ ctxpart, const float* __restrict__ epart,
    short* __restrict__ ctxb16)
{
  __shared__ float red[256];
  __shared__ float invs;
  const int bo = blockIdx.x;           // b*64 + o (128 blocks)
  const int b = bo >> 6, o = bo & 63;
  const int tid = threadIdx.x;
  // esum total: one chunk per thread
  red[tid] = epart[(((b << 8) + tid) << 6) + o];
  __syncthreads();
  if (tid < 64) {
    float v = red[tid] + red[tid + 64] + red[tid + 128] + red[tid + 192];
#pragma unroll
    for (int m = 1; m <= 32; m <<= 1) v += __shfl_xor(v, m, 64);
    if (tid == 0) invs = 1.f / v;
  }
  __syncthreads();
  const float inv = invs;
  // ctx sums: c = tid&63, 4 chunk-groups
  const int c = tid & 63, cg = tid >> 6;
  const float* p = ctxpart + ((size_t)b << 20) + (o << 6) + c;
  float s = 0.f;
  for (int ch = cg * 64; ch < cg * 64 + 64; ++ch) s += p[(size_t)ch << 12];
  __syncthreads();
  red[tid] = s;
  __syncthreads();
  if (tid < 64) {
    const float v = red[tid] + red[tid + 64] + red[tid + 128] + red[tid + 192];
    ctxb16[(bo << 6) + tid] = f2bf(v * inv);   // ctx_g[b][o][c]
  }
}

// ===========================================================================
extern "C" void kernel_launch(void* const* d_in, const int* in_sizes, int n_in,
                              void* d_out, int out_size, void* d_ws, size_t ws_size,
                              hipStream_t stream) {
  const float* x  = (const float*)d_in[0];
  const float* Wq = (const float*)d_in[1];
  const float* Wk = (const float*)d_in[2];
  const float* Wv = (const float*)d_in[3];
  const float* Wo = (const float*)d_in[4];
  const float* qw = (const float*)d_in[7];
  const float* qb = (const float*)d_in[8];
  const float* fw = (const float*)d_in[9];
  const float* fb = (const float*)d_in[10];
  const float* dw = (const float*)d_in[11];
  float* out = (float*)d_out;

  float* ws = (float*)d_ws;
  float* ctxpart = ws;                       // 2*256*4096 f32 = 8MB
  float* epart   = ctxpart + 2097152;        // 2*256*64 f32 = 128KB
  short* wbuf    = (short*)(epart + 32768);
  short* Wt3  = wbuf;                        // 24576
  short* Wvb  = Wt3 + 24576;                 // 12288
  short* WoT2 = Wvb + 12288;                 // 12288
  short* fwb  = WoT2 + 12288;                // 4096
  short* qwb  = fwb + 4096;                  // 4096
  short* ctxb16 = qwb + 4096;                // 8192

  hipLaunchKernelGGL(prep_w, dim3(96), dim3(256), 0, stream,
                     Wq, Wk, Wv, Wo, fw, qw, Wt3, Wvb, WoT2, fwb, qwb);
  hipLaunchKernelGGL(fmam_ctx1, dim3(256, 2), dim3(256), 0, stream,
                     x, fwb, fb, ctxpart, epart);
  hipLaunchKernelGGL(fmam_ctxreduce2, dim3(128), dim3(256), 0, stream,
                     ctxpart, epart, ctxb16);
  hipLaunchKernelGGL(attn_fused, dim3(2048), dim3(256), 0, stream,
                     x, Wt3, Wvb, WoT2, qwb, qb, ctxb16, dw, out);
}

// Round 7
// 115.071 us; speedup vs baseline: 6.6021x; 1.0866x over previous
//
#include <hip/hip_runtime.h>
#include <hip/hip_bf16.h>

// ---------------------------------------------------------------------------
// FPSAttn. LSH machinery is a no-op (full attention over the permuted patch,
// inverse-permuted; rounds identical, probs==0.5).
//   out = spa*dw0 + freq*dw1
//   spa  = patch 4-head attention + Wo   (fused kernel, wave-per-head)
//   freq = FMAM; ctx via SINGLE-PASS no-max softmax (|logit| <= ~1, exp safe),
//          queries-softmax fused into the attention epilogue.
// MFMA frag conventions (HW-verified rounds 1-6):
//   A-frag: lane(l15,l4) holds A[16*rt + l15][32*ks + 8*l4 + j], j=0..7
//   B-frag: lane holds B[32*ks + 8*l4 + j][16*ct + l15]
//   C-frag: lane holds C[16*rt + 4*l4 + r][16*ct + l15], r=0..3
// Repack identity (HW-verified): C-frag of Z (row R, col Q) -> A/B-frag of
// Z as [k=R][l15=Q] via same-l15 lane permutation (srcA/srcB/hi below).
// Round-6 lesson: forcing min-waves=4 spilled (VGPR 64, WRITE 2x). This round:
// natural VGPR + LDS-union (25.6KB -> 6 blocks/CU) + XCD patch swizzle.
// ---------------------------------------------------------------------------

typedef __attribute__((ext_vector_type(8))) short bf16x8;
typedef __attribute__((ext_vector_type(4))) float f32x4;
typedef __attribute__((ext_vector_type(4))) unsigned u32x4;

static __device__ __forceinline__ short f2bf(float f) {
  __hip_bfloat16 h = __float2bfloat16(f);
  return *reinterpret_cast<short*>(&h);
}
static __device__ __forceinline__ float bf2f(short s) {
  return __uint_as_float(((unsigned)(unsigned short)s) << 16);
}
// pack two f32 -> one u32 of 2 bf16 (low = a, high = b). Pure C++ (m240).
static __device__ __forceinline__ unsigned pack2bf(float a, float b) {
  return (unsigned)(unsigned short)f2bf(a) | ((unsigned)(unsigned short)f2bf(b) << 16);
}
static __device__ __forceinline__ f32x4 MFMA(bf16x8 a, bf16x8 b, f32x4 c) {
  return __builtin_amdgcn_mfma_f32_16x16x32_bf16(a, b, c, 0, 0, 0);
}

// swizzled byte offset into a [rows][64] bf16 LDS tile (128B rows)
#define LSWZ(row, bytecol) ((((row) << 7) + (bytecol)) ^ (((row) & 7) << 4))

// Repack two packed C-frag tiles (L = slab rows [0,16), H = rows [16,32))
// into an MFMA A/B-frag. pl0/pl1 = pack2bf(acc0,acc1)/(acc2,acc3).
static __device__ __forceinline__ bf16x8 repack(
    unsigned pl0, unsigned pl1, unsigned ph0, unsigned ph1,
    int srcA, int srcB, bool hi) {
  unsigned l0 = __shfl((int)pl0, srcA, 64), l1 = __shfl((int)pl1, srcA, 64);
  unsigned l2 = __shfl((int)pl0, srcB, 64), l3 = __shfl((int)pl1, srcB, 64);
  unsigned h0 = __shfl((int)ph0, srcA, 64), h1 = __shfl((int)ph1, srcA, 64);
  unsigned h2 = __shfl((int)ph0, srcB, 64), h3 = __shfl((int)ph1, srcB, 64);
  u32x4 v;
  v[0] = hi ? h0 : l0; v[1] = hi ? h1 : l1;
  v[2] = hi ? h2 : l2; v[3] = hi ? h3 : l3;
  return __builtin_bit_cast(bf16x8, v);
}
// variant: H tile is all-zero (K-padding)
static __device__ __forceinline__ bf16x8 repack1(
    unsigned pl0, unsigned pl1, int srcA, int srcB, bool hi) {
  unsigned l0 = __shfl((int)pl0, srcA, 64), l1 = __shfl((int)pl1, srcA, 64);
  unsigned l2 = __shfl((int)pl0, srcB, 64), l3 = __shfl((int)pl1, srcB, 64);
  u32x4 v;
  v[0] = hi ? 0u : l0; v[1] = hi ? 0u : l1;
  v[2] = hi ? 0u : l2; v[3] = hi ? 0u : l3;
  return __builtin_bit_cast(bf16x8, v);
}

// frag of x from global [c][n]: lane supplies x[c0+j][n]
static __device__ __forceinline__ bf16x8 load_xfrag(const float* xg, int c0, int n) {
  bf16x8 r;
#pragma unroll
  for (int j = 0; j < 8; ++j) r[j] = f2bf(xg[((size_t)(c0 + j) << 16) + (size_t)n]);
  return r;
}

// ======================= W prep ============================================
// Wt3: [2][192][64]  WqT,WkT (row = global dim, col = c)
// Wvb: [h][dc][ks][lane][8] B-frag-ready Wv
// WoT2:[64 co][192 dg]  = Wo[dg][co]
// fwb/qwb: [o][c] bf16 native
__global__ __launch_bounds__(256) void prep_w(
    const float* __restrict__ Wq, const float* __restrict__ Wk,
    const float* __restrict__ Wv, const float* __restrict__ Wo,
    const float* __restrict__ fw, const float* __restrict__ qw,
    short* __restrict__ Wt3, short* __restrict__ Wvb,
    short* __restrict__ WoT2, short* __restrict__ fwb, short* __restrict__ qwb)
{
  int i = blockIdx.x * 256 + threadIdx.x;
  if (i < 24576) {
    int m = i / 12288, rem = i % 12288;
    int r = rem >> 6, c = rem & 63;
    const float* W = m ? Wk : Wq;
    Wt3[i] = f2bf(W[c * 192 + r]);
  }
  if (i < 12288) {
    int h = i / 3072, rem = i % 3072;
    int j = rem & 7, ln = (rem >> 3) & 63, dcks = rem >> 9;
    int dc = dcks >> 1, ks = dcks & 1;
    int c = 32 * ks + 8 * (ln >> 4) + j;
    int col = 48 * h + 16 * dc + (ln & 15);
    Wvb[i] = f2bf(Wv[c * 192 + col]);
  }
  if (i < 12288) {
    int co = i / 192, dg = i % 192;
    WoT2[i] = f2bf(Wo[dg * 64 + co]);
  }
  if (i < 4096) { fwb[i] = f2bf(fw[i]); qwb[i] = f2bf(qw[i]); }
}

// ================= fused attention + freq + combine ========================
// LDS: single 25600B buffer; x-tile (8KB, swizzled) lives in its head until
// all x reads complete, then PV overwrites it with the o-tile [64][200].
__global__ __launch_bounds__(256) void attn_fused(
    const float* __restrict__ x, const short* __restrict__ Wt3,
    const short* __restrict__ Wvb, const short* __restrict__ WoT2,
    const short* __restrict__ qwb, const float* __restrict__ qbias,
    const short* __restrict__ ctxb16, const float* __restrict__ dw,
    float* __restrict__ out)
{
  __shared__ __align__(16) char ob_[25600];    // union: xb (first 8KB) / o-tile
  char* xb_ = ob_;

  const int tid = threadIdx.x, lane = tid & 63, w = tid >> 6;
  const int l15 = lane & 15, l4 = lane >> 4;
  const int srcA = l15 + 32 * (l4 & 1), srcB = srcA + 16;
  const bool hi = (l4 & 2) != 0;

  // XCD-aware swizzle (2048 % 8 == 0, bijective): consecutive patches share
  // 64B x-lines; keep them on the same XCD's L2.
  const int pid0 = blockIdx.x;
  const int pid = (pid0 & 7) * 256 + (pid0 >> 3);
  const int b = pid >> 10, prem = pid & 1023;
  const int y0 = (prem >> 5) << 3, x0 = (prem & 31) << 3;
  const float* xg = x + ((size_t)b << 22);

  // ---- stage x -> xb[t][c] ----
#pragma unroll
  for (int k = 0; k < 16; ++k) {
    int idx = tid + (k << 8);
    int c = idx >> 6, t = idx & 63;
    float v = xg[((size_t)c << 16) + (size_t)((y0 + (t >> 3)) * 256 + x0 + (t & 7))];
    *(short*)(xb_ + LSWZ(t, c * 2)) = f2bf(v);
  }
  __syncthreads();

  const int h = w;   // wave = head

  // ---- qT, kT:  ZT[d][t] = sum_c WT[d][c] x[t][c]  (C: col=t, row=d) ----
  unsigned qpk[3][4][2], kpk[3][4][2];
#pragma unroll
  for (int m = 0; m < 2; ++m) {
    const short* WT = Wt3 + m * 12288 + (48 * h) * 64;
    bf16x8 a[3][2];
#pragma unroll
    for (int rp = 0; rp < 3; ++rp)
#pragma unroll
      for (int ks = 0; ks < 2; ++ks)
        a[rp][ks] = *(const bf16x8*)(WT + (16 * rp + l15) * 64 + 32 * ks + 8 * l4);
#pragma unroll
    for (int cq = 0; cq < 4; ++cq) {
      bf16x8 b0 = *(const bf16x8*)(xb_ + LSWZ(16 * cq + l15, 16 * l4));
      bf16x8 b1 = *(const bf16x8*)(xb_ + LSWZ(16 * cq + l15, 64 + 16 * l4));
#pragma unroll
      for (int rp = 0; rp < 3; ++rp) {
        f32x4 acc = (f32x4)0.f;
        acc = MFMA(a[rp][0], b0, acc);
        acc = MFMA(a[rp][1], b1, acc);
        unsigned* dst = m ? kpk[rp][cq] : qpk[rp][cq];
        dst[0] = pack2bf(acc[0], acc[1]);
        dst[1] = pack2bf(acc[2], acc[3]);
      }
    }
  }

  // ---- S^T = k @ qT (K=48, ks1 half-zero); softmax over u; pack P^T ----
  unsigned ppk[4][4][2];
  {
    bf16x8 Bq[4][2];
#pragma unroll
    for (int tt = 0; tt < 4; ++tt) {
      Bq[tt][0] = repack(qpk[0][tt][0], qpk[0][tt][1], qpk[1][tt][0], qpk[1][tt][1], srcA, srcB, hi);
      Bq[tt][1] = repack1(qpk[2][tt][0], qpk[2][tt][1], srcA, srcB, hi);
    }
    f32x4 st[4][4];
#pragma unroll
    for (int ur = 0; ur < 4; ++ur) {
      bf16x8 A0 = repack(kpk[0][ur][0], kpk[0][ur][1], kpk[1][ur][0], kpk[1][ur][1], srcA, srcB, hi);
      bf16x8 A1 = repack1(kpk[2][ur][0], kpk[2][ur][1], srcA, srcB, hi);
#pragma unroll
      for (int tt = 0; tt < 4; ++tt) {
        f32x4 acc = (f32x4)0.f;
        acc = MFMA(A0, Bq[tt][0], acc);
        acc = MFMA(A1, Bq[tt][1], acc);
        st[ur][tt] = acc;
      }
    }
#pragma unroll
    for (int tt = 0; tt < 4; ++tt) {
      float m = st[0][tt][0];
#pragma unroll
      for (int ur = 0; ur < 4; ++ur)
#pragma unroll
        for (int r = 0; r < 4; ++r) m = fmaxf(m, st[ur][tt][r]);
      m = fmaxf(m, __shfl_xor(m, 16, 64));
      m = fmaxf(m, __shfl_xor(m, 32, 64));
      float s = 0.f;
#pragma unroll
      for (int ur = 0; ur < 4; ++ur)
#pragma unroll
        for (int r = 0; r < 4; ++r) {
          float e = __expf(st[ur][tt][r] - m);
          st[ur][tt][r] = e; s += e;
        }
      s += __shfl_xor(s, 16, 64);
      s += __shfl_xor(s, 32, 64);
      const float inv = 1.f / s;
#pragma unroll
      for (int ur = 0; ur < 4; ++ur) {
        ppk[ur][tt][0] = pack2bf(st[ur][tt][0] * inv, st[ur][tt][1] * inv);
        ppk[ur][tt][1] = pack2bf(st[ur][tt][2] * inv, st[ur][tt][3] * inv);
      }
    }
  }

  // ---- v[u][d] = sum_c x[u][c] Wv[c][d]  (C: col=d, row=u) ----
  unsigned vpk[4][3][2];
  {
    const short* Wvh = Wvb + h * 3072;
    bf16x8 bv[3][2];
#pragma unroll
    for (int dc = 0; dc < 3; ++dc)
#pragma unroll
      for (int ks = 0; ks < 2; ++ks)
        bv[dc][ks] = *(const bf16x8*)(Wvh + ((dc * 2 + ks) * 64 + lane) * 8);
#pragma unroll
    for (int ur = 0; ur < 4; ++ur) {
      bf16x8 a0 = *(const bf16x8*)(xb_ + LSWZ(16 * ur + l15, 16 * l4));
      bf16x8 a1 = *(const bf16x8*)(xb_ + LSWZ(16 * ur + l15, 64 + 16 * l4));
#pragma unroll
      for (int dc = 0; dc < 3; ++dc) {
        f32x4 acc = (f32x4)0.f;
        acc = MFMA(a0, bv[dc][0], acc);
        acc = MFMA(a1, bv[dc][1], acc);
        vpk[ur][dc][0] = pack2bf(acc[0], acc[1]);
        vpk[ur][dc][1] = pack2bf(acc[2], acc[3]);
      }
    }
  }

  // ---- z (queries logits) for t-strip w: zT[o][t] = qw@x + qb; softmax(o) --
  // (last xb reader — must precede the barrier that frees the union buffer)
  unsigned pzpk[4][2];
  {
    bf16x8 xz0 = *(const bf16x8*)(xb_ + LSWZ(16 * w + l15, 16 * l4));
    bf16x8 xz1 = *(const bf16x8*)(xb_ + LSWZ(16 * w + l15, 64 + 16 * l4));
    f32x4 zt[4];
#pragma unroll
    for (int orr = 0; orr < 4; ++orr) {
      bf16x8 a0 = *(const bf16x8*)(qwb + (16 * orr + l15) * 64 + 8 * l4);
      bf16x8 a1 = *(const bf16x8*)(qwb + (16 * orr + l15) * 64 + 32 + 8 * l4);
      f32x4 acc;
#pragma unroll
      for (int r = 0; r < 4; ++r) acc[r] = qbias[16 * orr + 4 * l4 + r];
      acc = MFMA(a0, xz0, acc);
      acc = MFMA(a1, xz1, acc);
      zt[orr] = acc;
    }
    float m = zt[0][0];
#pragma unroll
    for (int orr = 0; orr < 4; ++orr)
#pragma unroll
      for (int r = 0; r < 4; ++r) m = fmaxf(m, zt[orr][r]);
    m = fmaxf(m, __shfl_xor(m, 16, 64));
    m = fmaxf(m, __shfl_xor(m, 32, 64));
    float s = 0.f;
#pragma unroll
    for (int orr = 0; orr < 4; ++orr)
#pragma unroll
      for (int r = 0; r < 4; ++r) { float e = __expf(zt[orr][r] - m); zt[orr][r] = e; s += e; }
    s += __shfl_xor(s, 16, 64);
    s += __shfl_xor(s, 32, 64);
    const float inv = 1.f / s;
#pragma unroll
    for (int orr = 0; orr < 4; ++orr) {
      pzpk[orr][0] = pack2bf(zt[orr][0] * inv, zt[orr][1] * inv);
      pzpk[orr][1] = pack2bf(zt[orr][2] * inv, zt[orr][3] * inv);
    }
  }
  __syncthreads();   // all xb reads done; union buffer becomes o-tile

  // ---- oT = vT @ P^T  -> ob[t][48h+dloc]  (registers only + ob writes) ----
  {
    bf16x8 Bp[4][2];
#pragma unroll
    for (int tt = 0; tt < 4; ++tt) {
      Bp[tt][0] = repack(ppk[0][tt][0], ppk[0][tt][1], ppk[1][tt][0], ppk[1][tt][1], srcA, srcB, hi);
      Bp[tt][1] = repack(ppk[2][tt][0], ppk[2][tt][1], ppk[3][tt][0], ppk[3][tt][1], srcA, srcB, hi);
    }
#pragma unroll
    for (int dr = 0; dr < 3; ++dr) {
      bf16x8 A0 = repack(vpk[0][dr][0], vpk[0][dr][1], vpk[1][dr][0], vpk[1][dr][1], srcA, srcB, hi);
      bf16x8 A1 = repack(vpk[2][dr][0], vpk[2][dr][1], vpk[3][dr][0], vpk[3][dr][1], srcA, srcB, hi);
#pragma unroll
      for (int tt = 0; tt < 4; ++tt) {
        f32x4 acc = (f32x4)0.f;
        acc = MFMA(A0, Bp[tt][0], acc);
        acc = MFMA(A1, Bp[tt][1], acc);
        const int row = 16 * tt + l15;
        const int col = 48 * h + 16 * dr + 4 * l4;
        *(unsigned*)(ob_ + row * 400 + col * 2)     = pack2bf(acc[0], acc[1]);
        *(unsigned*)(ob_ + row * 400 + col * 2 + 4) = pack2bf(acc[2], acc[3]);
      }
    }
  }
  __syncthreads();

  // ---- outT[co][t] = WoT2 @ o_all (K=192); freqT = ctx @ Pz; combine ----
  {
    f32x4 ot[4], ft[4];
#pragma unroll
    for (int kr = 0; kr < 4; ++kr) { ot[kr] = (f32x4)0.f; ft[kr] = (f32x4)0.f; }
#pragma unroll
    for (int ks = 0; ks < 6; ++ks) {
      bf16x8 bo = *(const bf16x8*)(ob_ + (16 * w + l15) * 400 + 64 * ks + 16 * l4);
#pragma unroll
      for (int kr = 0; kr < 4; ++kr) {
        bf16x8 a = *(const bf16x8*)(WoT2 + (16 * kr + l15) * 192 + 32 * ks + 8 * l4);
        ot[kr] = MFMA(a, bo, ot[kr]);
      }
    }
    {
      bf16x8 Bz0 = repack(pzpk[0][0], pzpk[0][1], pzpk[1][0], pzpk[1][1], srcA, srcB, hi);
      bf16x8 Bz1 = repack(pzpk[2][0], pzpk[2][1], pzpk[3][0], pzpk[3][1], srcA, srcB, hi);
      const short* cb = ctxb16 + ((size_t)b << 12);
#pragma unroll
      for (int kr = 0; kr < 4; ++kr) {
        bf16x8 a0 = *(const bf16x8*)(cb + (16 * kr + l15) * 64 + 8 * l4);
        bf16x8 a1 = *(const bf16x8*)(cb + (16 * kr + l15) * 64 + 32 + 8 * l4);
        ft[kr] = MFMA(a0, Bz0, ft[kr]);
        ft[kr] = MFMA(a1, Bz1, ft[kr]);
      }
    }
    const int t = 16 * w + l15;
    const size_t nbase = (size_t)((y0 + (t >> 3)) * 256 + x0 + (t & 7));
    float* og = out + ((size_t)b << 22);
#pragma unroll
    for (int kr = 0; kr < 4; ++kr)
#pragma unroll
      for (int r = 0; r < 4; ++r) {
        const int co = 16 * kr + 4 * l4 + r;
        og[((size_t)co << 16) + nbase] = ot[kr][r] * dw[2 * co] + ft[kr][r] * dw[2 * co + 1];
      }
  }
}

// ========== FMAM single-pass: ctx partials + esum (no-max softmax) =========
// Per (b, chunk of 256 n), wave strip = 64 n. For each 32-n slab:
//   Y^T[n][o] = x^T @ fw^T + fb  (MFMA, C: row=n, col=o)
//   E = exp(Y) in-register (|Y| <~ 1, overflow-free), repack -> B-frag [n][o]
//   ctx[c][o] += x-frag[c][n] @ E[n][o]   (MFMA)
// Wave partials reduced across waves in LDS; per-chunk [o][c] + esum[o] out.
__global__ __launch_bounds__(256) void fmam_ctx1(
    const float* __restrict__ x, const short* __restrict__ fwb,
    const float* __restrict__ fb, float* __restrict__ ctxpart,
    float* __restrict__ epart)
{
  __shared__ float cred[4][64 * 68];   // [wave][o*68 + c] (pad 68: 2-way banks)
  __shared__ float ered[4][64];
  const int tid = threadIdx.x, lane = tid & 63, w = tid >> 6;
  const int l15 = lane & 15, l4 = lane >> 4;
  const int srcA = l15 + 32 * (l4 & 1), srcB = srcA + 16;
  const bool hi = (l4 & 2) != 0;
  const int chunk = blockIdx.x, b = blockIdx.y;
  const float* xg = x + ((size_t)b << 22);
  const int n0 = (chunk << 8) + (w << 6);

  // B-frags of fw^T: B[c][o] = fw[o][c] -> contiguous in fwb[o*64+c]
  bf16x8 Bfw[4][2];
#pragma unroll
  for (int ct = 0; ct < 4; ++ct)
#pragma unroll
    for (int ks = 0; ks < 2; ++ks)
      Bfw[ct][ks] = *(const bf16x8*)(fwb + (16 * ct + l15) * 64 + 32 * ks + 8 * l4);
  float fbl[4];
#pragma unroll
  for (int ct = 0; ct < 4; ++ct) fbl[ct] = fb[16 * ct + l15];

  f32x4 acc[4][4];   // [rt2 c-tile][ct o-tile]
#pragma unroll
  for (int i = 0; i < 4; ++i)
#pragma unroll
    for (int j = 0; j < 4; ++j) acc[i][j] = (f32x4)0.f;
  float esum[4] = {0.f, 0.f, 0.f, 0.f};

#pragma unroll
  for (int ns = 0; ns < 2; ++ns) {
    const int nb = n0 + 32 * ns;
    // A-frags x^T (row n, k c): lane j -> x[32ks+8l4+j][nb+16rt+l15]
    bf16x8 axT[2][2];
#pragma unroll
    for (int rt = 0; rt < 2; ++rt)
#pragma unroll
      for (int ks = 0; ks < 2; ++ks)
        axT[rt][ks] = load_xfrag(xg, 32 * ks + 8 * l4, nb + 16 * rt + l15);
    unsigned pl[4][2][2];   // [ct][rt(L/H)][pair]
#pragma unroll
    for (int rt = 0; rt < 2; ++rt)
#pragma unroll
      for (int ct = 0; ct < 4; ++ct) {
        f32x4 yt = (f32x4)(fbl[ct]);
        yt = MFMA(axT[rt][0], Bfw[ct][0], yt);
        yt = MFMA(axT[rt][1], Bfw[ct][1], yt);
        float e0 = __expf(yt[0]), e1 = __expf(yt[1]);
        float e2 = __expf(yt[2]), e3 = __expf(yt[3]);
        esum[ct] += (e0 + e1) + (e2 + e3);
        pl[ct][rt][0] = pack2bf(e0, e1);
        pl[ct][rt][1] = pack2bf(e2, e3);
      }
    // A-frags x (row c, k n): contiguous float4x2 per lane
    bf16x8 axc[4];
#pragma unroll
    for (int rt2 = 0; rt2 < 4; ++rt2) {
      const float* xr = xg + ((size_t)(16 * rt2 + l15) << 16) + nb + 8 * l4;
      const float4 a4 = *(const float4*)xr;
      const float4 b4 = *(const float4*)(xr + 4);
      bf16x8 f;
      f[0] = f2bf(a4.x); f[1] = f2bf(a4.y); f[2] = f2bf(a4.z); f[3] = f2bf(a4.w);
      f[4] = f2bf(b4.x); f[5] = f2bf(b4.y); f[6] = f2bf(b4.z); f[7] = f2bf(b4.w);
      axc[rt2] = f;
    }
#pragma unroll
    for (int ct = 0; ct < 4; ++ct) {
      bf16x8 Bp = repack(pl[ct][0][0], pl[ct][0][1], pl[ct][1][0], pl[ct][1][1],
                         srcA, srcB, hi);
#pragma unroll
      for (int rt2 = 0; rt2 < 4; ++rt2)
        acc[rt2][ct] = MFMA(axc[rt2], Bp, acc[rt2][ct]);
    }
  }
  // esum: reduce across l4 groups (rows); lane l15 of each group has o-total
#pragma unroll
  for (int ct = 0; ct < 4; ++ct) {
    esum[ct] += __shfl_xor(esum[ct], 16, 64);
    esum[ct] += __shfl_xor(esum[ct], 32, 64);
  }
  if (l4 == 0) {
#pragma unroll
    for (int ct = 0; ct < 4; ++ct) ered[w][16 * ct + l15] = esum[ct];
  }
  // ctx partials -> LDS (C-frag: row=c=16rt2+4l4+r, col=o=16ct+l15)
#pragma unroll
  for (int ct = 0; ct < 4; ++ct)
#pragma unroll
    for (int rt2 = 0; rt2 < 4; ++rt2)
      *(f32x4*)&cred[w][(16 * ct + l15) * 68 + 16 * rt2 + 4 * l4] = acc[rt2][ct];
  __syncthreads();
  // combine 4 waves, write per-chunk partials
  float* cp = ctxpart + ((((size_t)b << 8) + chunk) << 12);
  for (int i = tid; i < 4096; i += 256) {
    const int o = i >> 6, c = i & 63;
    const int li = o * 68 + c;
    cp[i] = (cred[0][li] + cred[1][li]) + (cred[2][li] + cred[3][li]);
  }
  if (tid < 64)
    epart[(((b << 8) + chunk) << 6) + tid] =
        (ered[0][tid] + ered[1][tid]) + (ered[2][tid] + ered[3][tid]);
}

// ====== reduce ctx partials over chunks, divide by esum, emit bf16 ========
__global__ __launch_bounds__(256) void fmam_ctxreduce2(
    const float* __restrict__ ctxpart, const float* __restrict__ epart,
    short* __restrict__ ctxb16)
{
  __shared__ float red[256];
  __shared__ float invs;
  const int bo = blockIdx.x;           // b*64 + o (128 blocks)
  const int b = bo >> 6, o = bo & 63;
  const int tid = threadIdx.x;
  // esum total: one chunk per thread
  red[tid] = epart[(((b << 8) + tid) << 6) + o];
  __syncthreads();
  if (tid < 64) {
    float v = red[tid] + red[tid + 64] + red[tid + 128] + red[tid + 192];
#pragma unroll
    for (int m = 1; m <= 32; m <<= 1) v += __shfl_xor(v, m, 64);
    if (tid == 0) invs = 1.f / v;
  }
  __syncthreads();
  const float inv = invs;
  // ctx sums: c = tid&63, 4 chunk-groups
  const int c = tid & 63, cg = tid >> 6;
  const float* p = ctxpart + ((size_t)b << 20) + (o << 6) + c;
  float s = 0.f;
  for (int ch = cg * 64; ch < cg * 64 + 64; ++ch) s += p[(size_t)ch << 12];
  __syncthreads();
  red[tid] = s;
  __syncthreads();
  if (tid < 64) {
    const float v = red[tid] + red[tid + 64] + red[tid + 128] + red[tid + 192];
    ctxb16[(bo << 6) + tid] = f2bf(v * inv);   // ctx_g[b][o][c]
  }
}

// ===========================================================================
extern "C" void kernel_launch(void* const* d_in, const int* in_sizes, int n_in,
                              void* d_out, int out_size, void* d_ws, size_t ws_size,
                              hipStream_t stream) {
  const float* x  = (const float*)d_in[0];
  const float* Wq = (const float*)d_in[1];
  const float* Wk = (const float*)d_in[2];
  const float* Wv = (const float*)d_in[3];
  const float* Wo = (const float*)d_in[4];
  const float* qw = (const float*)d_in[7];
  const float* qb = (const float*)d_in[8];
  const float* fw = (const float*)d_in[9];
  const float* fb = (const float*)d_in[10];
  const float* dw = (const float*)d_in[11];
  float* out = (float*)d_out;

  float* ws = (float*)d_ws;
  float* ctxpart = ws;                       // 2*256*4096 f32 = 8MB
  float* epart   = ctxpart + 2097152;        // 2*256*64 f32 = 128KB
  short* wbuf    = (short*)(epart + 32768);
  short* Wt3  = wbuf;                        // 24576
  short* Wvb  = Wt3 + 24576;                 // 12288
  short* WoT2 = Wvb + 12288;                 // 12288
  short* fwb  = WoT2 + 12288;                // 4096
  short* qwb  = fwb + 4096;                  // 4096
  short* ctxb16 = qwb + 4096;                // 8192

  hipLaunchKernelGGL(prep_w, dim3(96), dim3(256), 0, stream,
                     Wq, Wk, Wv, Wo, fw, qw, Wt3, Wvb, WoT2, fwb, qwb);
  hipLaunchKernelGGL(fmam_ctx1, dim3(256, 2), dim3(256), 0, stream,
                     x, fwb, fb, ctxpart, epart);
  hipLaunchKernelGGL(fmam_ctxreduce2, dim3(128), dim3(256), 0, stream,
                     ctxpart, epart, ctxb16);
  hipLaunchKernelGGL(attn_fused, dim3(2048), dim3(256), 0, stream,
                     x, Wt3, Wvb, WoT2, qwb, qb, ctxb16, dw, out);
}